// Round 1
// baseline (2672.882 us; speedup 1.0000x reference)
//
#include <hip/hip_runtime.h>
#include <math.h>

#define N_ING 100000
#define N_DIR 50000
#define NE    1000000
#define HID   64
#define LAT   32
#define CONDN 8

// ---------------- projection: h = x @ W + b ----------------
// one thread per (node, f) output element; W,b staged in LDS
__global__ __launch_bounds__(256) void proj_kernel(
    const float* __restrict__ x, const float* __restrict__ W,
    const float* __restrict__ b, float* __restrict__ h, int N, int F)
{
    __shared__ float sW[16 * 64];
    __shared__ float sb[64];
    for (int i = threadIdx.x; i < F * 64; i += blockDim.x) sW[i] = W[i];
    if (threadIdx.x < 64) sb[threadIdx.x] = b[threadIdx.x];
    __syncthreads();
    int idx = blockIdx.x * blockDim.x + threadIdx.x;
    if (idx >= N * 64) return;
    int n = idx >> 6, f = idx & 63;
    const float* xr = x + (size_t)n * F;
    float s = sb[f];
    for (int i = 0; i < F; ++i) s += xr[i] * sW[i * 64 + f];
    h[idx] = s;
}

// ---------------- attention score precompute ----------------
// s[n, slot, h] = sum_d h[n, h*16+d] * att_slot[h*16+d]
__global__ __launch_bounds__(256) void score_ing_kernel(
    const float* __restrict__ h, float* __restrict__ s, int N,
    const float* __restrict__ a0, const float* __restrict__ a1,
    const float* __restrict__ a2)
{
    int idx = blockIdx.x * blockDim.x + threadIdx.x;  // n*4 + head
    if (idx >= N * 4) return;
    int n = idx >> 2, hh = idx & 3;
    const float* row = h + (size_t)n * 64 + hh * 16;
    float d0 = 0.f, d1 = 0.f, d2 = 0.f;
    for (int d = 0; d < 16; ++d) {
        float v = row[d];
        d0 += v * a0[hh * 16 + d];
        d1 += v * a1[hh * 16 + d];
        d2 += v * a2[hh * 16 + d];
    }
    float* sr = s + (size_t)n * 12;
    sr[0 + hh] = d0;
    sr[4 + hh] = d1;
    sr[8 + hh] = d2;
}

__global__ __launch_bounds__(256) void score_dir_kernel(
    const float* __restrict__ h, float* __restrict__ s, int N,
    const float* __restrict__ a0, const float* __restrict__ a1,
    const float* __restrict__ a2, const float* __restrict__ a3,
    const float* __restrict__ a4, const float* __restrict__ a5,
    const float* __restrict__ a6)
{
    int idx = blockIdx.x * blockDim.x + threadIdx.x;
    if (idx >= N * 4) return;
    int n = idx >> 2, hh = idx & 3;
    const float* row = h + (size_t)n * 64 + hh * 16;
    float d0 = 0.f, d1 = 0.f, d2 = 0.f, d3 = 0.f, d4 = 0.f, d5 = 0.f, d6 = 0.f;
    for (int d = 0; d < 16; ++d) {
        float v = row[d];
        d0 += v * a0[hh * 16 + d];
        d1 += v * a1[hh * 16 + d];
        d2 += v * a2[hh * 16 + d];
        d3 += v * a3[hh * 16 + d];
        d4 += v * a4[hh * 16 + d];
        d5 += v * a5[hh * 16 + d];
        d6 += v * a6[hh * 16 + d];
    }
    float* sr = s + (size_t)n * 28;
    sr[0  + hh] = d0;
    sr[4  + hh] = d1;
    sr[8  + hh] = d2;
    sr[12 + hh] = d3;
    sr[16 + hh] = d4;
    sr[20 + hh] = d5;
    sr[24 + hh] = d6;
}

// ---------------- edge pass 1: ex = exp(leaky_relu(s_src+s_dst)); denom += ex
__global__ __launch_bounds__(256) void edge1_kernel(
    const int* __restrict__ ei,
    const float* __restrict__ s_src, int ss_stride, int ss_off,
    const float* __restrict__ s_dst, int ds_stride, int ds_off,
    float* __restrict__ ex, float* __restrict__ denom)
{
    int e = blockIdx.x * blockDim.x + threadIdx.x;
    if (e >= NE) return;
    int src = ei[e], dst = ei[NE + e];
    const float* a = s_src + (size_t)src * ss_stride + ss_off;
    const float* b = s_dst + (size_t)dst * ds_stride + ds_off;
    float4 ev;
    float* evp = (float*)&ev;
#pragma unroll
    for (int h = 0; h < 4; ++h) {
        float v = a[h] + b[h];
        v = v > 0.f ? v : 0.2f * v;   // leaky_relu(0.2)
        float e1 = expf(v);           // no max-shift needed: |v| is O(1)
        evp[h] = e1;
        atomicAdd(&denom[(size_t)dst * 4 + h], e1);
    }
    *(float4*)&ex[(size_t)e * 4] = ev;
}

// ---------------- edge pass 2: acc[dst,:] += h_src[src,:] * alpha ----------
// 64 threads per edge (one per feature)
__global__ __launch_bounds__(256) void edge2_kernel(
    const int* __restrict__ ei, const float* __restrict__ h_src,
    const float* __restrict__ ex, const float* __restrict__ denom,
    float* __restrict__ acc)
{
    int gid = blockIdx.x * blockDim.x + threadIdx.x;
    int e = gid >> 6;
    if (e >= NE) return;
    int t = gid & 63, h = t >> 4;
    int src = ei[e], dst = ei[NE + e];
    float alpha = ex[(size_t)e * 4 + h] / (denom[(size_t)dst * 4 + h] + 1e-16f);
    atomicAdd(&acc[(size_t)dst * 64 + t], h_src[(size_t)src * 64 + t] * alpha);
}

// ---------------- reduce (ingredient dst type): pool_sum[f] += relu(acc) ----
__global__ __launch_bounds__(256) void reduce_pool_kernel(
    const float* __restrict__ acc, int N, float* __restrict__ pool_sum)
{
    __shared__ float sh[4][64];
    int f = threadIdx.x & 63, g = threadIdx.x >> 6;
    float local = 0.f;
    for (long n = (long)blockIdx.x * 4 + g; n < N; n += (long)gridDim.x * 4)
        local += fmaxf(acc[n * 64 + f], 0.f);
    sh[g][f] = local;
    __syncthreads();
    if (g == 0)
        atomicAdd(&pool_sum[f], sh[0][f] + sh[1][f] + sh[2][f] + sh[3][f]);
}

// ---------------- reduce (direction dst type): pool + semantic sums --------
__global__ __launch_bounds__(256) void reduce_dir_kernel(
    const float* __restrict__ acc, int N,
    const float* __restrict__ Wk, const float* __restrict__ bk,
    float* __restrict__ pool_sum, float* __restrict__ sem_sum)
{
    __shared__ float sWk[64 * 64];
    __shared__ float srow[4][64];
    for (int i = threadIdx.x; i < 4096; i += blockDim.x) sWk[i] = Wk[i];
    int f = threadIdx.x & 63, g = threadIdx.x >> 6;
    float bkf = bk[f];
    float pool = 0.f, sem = 0.f;
    __syncthreads();
    for (long base = (long)blockIdx.x * 4; base < N; base += (long)gridDim.x * 4) {
        long n = base + g;
        float v = (n < N) ? fmaxf(acc[n * 64 + f], 0.f) : 0.f;
        srow[g][f] = v;
        pool += v;
        __syncthreads();
        if (n < N) {
            float a2 = bkf;
#pragma unroll 8
            for (int k = 0; k < 64; ++k) a2 += srow[g][k] * sWk[k * 64 + f];
            sem += tanhf(a2);
        }
        __syncthreads();
    }
    srow[g][f] = pool;
    __syncthreads();
    if (g == 0)
        atomicAdd(&pool_sum[f], srow[0][f] + srow[1][f] + srow[2][f] + srow[3][f]);
    __syncthreads();
    srow[g][f] = sem;
    __syncthreads();
    if (g == 0)
        atomicAdd(&sem_sum[f], srow[0][f] + srow[1][f] + srow[2][f] + srow[3][f]);
}

// ---------------- final: semantic softmax + pools + VAE head ----------------
__global__ __launch_bounds__(64) void final_kernel(
    const float* __restrict__ pool_ing, const float* __restrict__ pool_dir,
    const float* __restrict__ sem_dir, const float* __restrict__ q,
    const float* __restrict__ cond, const float* __restrict__ eps,
    const float* __restrict__ W_mu, const float* __restrict__ b_mu,
    const float* __restrict__ W_lv, const float* __restrict__ b_lv,
    const float* __restrict__ W_fc3, const float* __restrict__ b_fc3,
    const float* __restrict__ W_fc2, const float* __restrict__ b_fc2,
    float* __restrict__ out)
{
    __shared__ float gr[136];
    __shared__ float sc[4], attn[4];
    __shared__ float z[32], hfc[64];
    int t = threadIdx.x;  // 64 threads
    if (t < 4) {
        float s = 0.f;
        for (int f = 0; f < 64; ++f)
            s += (sem_dir[t * 64 + f] / (float)N_DIR) * q[f];
        sc[t] = s;
    }
    gr[t] = pool_ing[t] / (float)N_ING;   // out_ing == o_cont (T=1 softmax)
    __syncthreads();
    if (t == 0) {
        float m = fmaxf(fmaxf(sc[0], sc[1]), fmaxf(sc[2], sc[3]));
        float ssum = 0.f;
        for (int i = 0; i < 4; ++i) { attn[i] = expf(sc[i] - m); ssum += attn[i]; }
        for (int i = 0; i < 4; ++i) attn[i] /= ssum;
    }
    __syncthreads();
    {
        float v = 0.f;
        for (int tt = 0; tt < 4; ++tt)
            v += attn[tt] * (pool_dir[tt * 64 + t] / (float)N_DIR);
        gr[64 + t] = v;
    }
    if (t < 8) gr[128 + t] = cond[t];
    __syncthreads();
    if (t < 32) {
        float m = b_mu[t], lv = b_lv[t];
        for (int i = 0; i < 136; ++i) {
            float g = gr[i];
            m  += g * W_mu[i * 32 + t];
            lv += g * W_lv[i * 32 + t];
        }
        out[16 + t] = m;
        out[48 + t] = lv;
        z[t] = m + eps[t] * expf(0.5f * lv);
    }
    __syncthreads();
    {
        float v = b_fc3[t];
        for (int j = 0; j < 32; ++j) v += z[j] * W_fc3[j * 64 + t];
        hfc[t] = fmaxf(v, 0.f);
    }
    __syncthreads();
    if (t < 16) {
        float v = b_fc2[t];
        for (int f = 0; f < 64; ++f) v += hfc[f] * W_fc2[f * 16 + t];
        out[t] = tanhf(v);
    }
}

extern "C" void kernel_launch(void* const* d_in, const int* in_sizes, int n_in,
                              void* d_out, int out_size, void* d_ws, size_t ws_size,
                              hipStream_t stream) {
    const float* x_ing = (const float*)d_in[0];
    const float* x_dir = (const float*)d_in[1];
    const float* cond  = (const float*)d_in[2];
    const float* eps   = (const float*)d_in[3];
    const int* ei_cooc     = (const int*)d_in[4];
    const int* ei_used     = (const int*)d_in[5];
    const int* ei_contains = (const int*)d_in[6];
    const int* ei_pairs    = (const int*)d_in[7];
    const int* ei_follows  = (const int*)d_in[8];
    const float* W_pi = (const float*)d_in[9];
    const float* b_pi = (const float*)d_in[10];
    const float* W_pd = (const float*)d_in[11];
    const float* b_pd = (const float*)d_in[12];
    const float* Wk   = (const float*)d_in[13];
    const float* bk   = (const float*)d_in[14];
    const float* q    = (const float*)d_in[15];
    const float* W_mu = (const float*)d_in[16];
    const float* b_mu = (const float*)d_in[17];
    const float* W_lv = (const float*)d_in[18];
    const float* b_lv = (const float*)d_in[19];
    const float* W_fc3 = (const float*)d_in[20];
    const float* b_fc3 = (const float*)d_in[21];
    const float* W_fc2 = (const float*)d_in[22];
    const float* b_fc2 = (const float*)d_in[23];
    const float* as_cooc     = (const float*)d_in[24];
    const float* ad_cooc     = (const float*)d_in[25];
    const float* as_used     = (const float*)d_in[26];
    const float* ad_used     = (const float*)d_in[27];
    const float* as_contains = (const float*)d_in[28];
    const float* ad_contains = (const float*)d_in[29];
    const float* as_pairs    = (const float*)d_in[30];
    const float* ad_pairs    = (const float*)d_in[31];
    const float* as_follows  = (const float*)d_in[32];
    const float* ad_follows  = (const float*)d_in[33];

    // ---- workspace layout (floats) ----
    float* ws = (float*)d_ws;
    float* h_ing = ws;                         // 6,400,000
    float* h_dir = h_ing + (size_t)N_ING * 64; // 3,200,000
    float* s_ing = h_dir + (size_t)N_DIR * 64; // 1,200,000  [N_ING][3][4]
    float* s_dir = s_ing + (size_t)N_ING * 12; // 1,400,000  [N_DIR][7][4]
    float* ex    = s_dir + (size_t)N_DIR * 28; // 4,000,000  [NE][4]
    float* acc   = ex    + (size_t)NE * 4;     // 6,400,000  (reused per type)
    float* denom = acc   + (size_t)N_ING * 64; //   400,000  (reused per type)
    float* pool_ing = denom + (size_t)N_ING * 4; // 64
    float* pool_dir = pool_ing + 64;             // 4*64
    float* sem_dir  = pool_dir + 256;            // 4*64

    // zero the tiny pooled-sum region (576 floats)
    hipMemsetAsync(pool_ing, 0, (64 + 256 + 256) * sizeof(float), stream);

    // projections
    proj_kernel<<<(N_ING * 64) / 256, 256, 0, stream>>>(x_ing, W_pi, b_pi, h_ing, N_ING, 16);
    proj_kernel<<<(N_DIR * 64) / 256, 256, 0, stream>>>(x_dir, W_pd, b_pd, h_dir, N_DIR, 8);

    // per-node attention scores
    // ing slots: 0 = src(cooc), 1 = src(used), 2 = dst(contains)
    score_ing_kernel<<<(N_ING * 4 + 255) / 256, 256, 0, stream>>>(
        h_ing, s_ing, N_ING, as_cooc, as_used, ad_contains);
    // dir slots: 0 = dst(cooc), 1 = dst(used), 2 = src(contains),
    //            3 = src(pairs), 4 = dst(pairs), 5 = src(follows), 6 = dst(follows)
    score_dir_kernel<<<(N_DIR * 4 + 255) / 256, 256, 0, stream>>>(
        h_dir, s_dir, N_DIR, ad_cooc, ad_used, as_contains, as_pairs, ad_pairs,
        as_follows, ad_follows);

    struct EdgeType {
        const int* ei;
        const float* ssrc; int sstride, soff;
        const float* sdst; int dstride, doff;
        const float* hsrc;
        int ndst;
        int dir_slot;  // -1 => ingredient-dst (contains)
    };
    EdgeType types[5] = {
        { ei_cooc,     s_ing, 12, 0,  s_dir, 28, 0,  h_ing, N_DIR,  0 },
        { ei_used,     s_ing, 12, 4,  s_dir, 28, 4,  h_ing, N_DIR,  1 },
        { ei_contains, s_dir, 28, 8,  s_ing, 12, 8,  h_dir, N_ING, -1 },
        { ei_pairs,    s_dir, 28, 12, s_dir, 28, 16, h_dir, N_DIR,  2 },
        { ei_follows,  s_dir, 28, 20, s_dir, 28, 24, h_dir, N_DIR,  3 },
    };

    for (int t = 0; t < 5; ++t) {
        EdgeType& et = types[t];
        hipMemsetAsync(acc, 0, (size_t)et.ndst * 64 * sizeof(float), stream);
        hipMemsetAsync(denom, 0, (size_t)et.ndst * 4 * sizeof(float), stream);
        edge1_kernel<<<(NE + 255) / 256, 256, 0, stream>>>(
            et.ei, et.ssrc, et.sstride, et.soff, et.sdst, et.dstride, et.doff,
            ex, denom);
        edge2_kernel<<<(NE * 64) / 256, 256, 0, stream>>>(
            et.ei, et.hsrc, ex, denom, acc);
        if (et.dir_slot < 0) {
            reduce_pool_kernel<<<256, 256, 0, stream>>>(acc, N_ING, pool_ing);
        } else {
            reduce_dir_kernel<<<250, 256, 0, stream>>>(
                acc, N_DIR, Wk, bk,
                pool_dir + et.dir_slot * 64, sem_dir + et.dir_slot * 64);
        }
    }

    final_kernel<<<1, 64, 0, stream>>>(
        pool_ing, pool_dir, sem_dir, q, cond, eps,
        W_mu, b_mu, W_lv, b_lv, W_fc3, b_fc3, W_fc2, b_fc2, (float*)d_out);
}

// Round 2
// 1394.589 us; speedup vs baseline: 1.9166x; 1.9166x over previous
//
#include <hip/hip_runtime.h>
#include <math.h>

#define N_ING 100000
#define N_DIR 50000
#define NE    1000000
#define NDST_TOTAL 300000   // 50K(cooc)+50K(used)+100K(contains)+50K(pairs)+50K(follows)

// ---------------- projection: h = x @ W + b ----------------
__global__ __launch_bounds__(256) void proj_kernel(
    const float* __restrict__ x, const float* __restrict__ W,
    const float* __restrict__ b, float* __restrict__ h, int N, int F)
{
    __shared__ float sW[16 * 64];
    __shared__ float sb[64];
    for (int i = threadIdx.x; i < F * 64; i += blockDim.x) sW[i] = W[i];
    if (threadIdx.x < 64) sb[threadIdx.x] = b[threadIdx.x];
    __syncthreads();
    int idx = blockIdx.x * blockDim.x + threadIdx.x;
    if (idx >= N * 64) return;
    int n = idx >> 6, f = idx & 63;
    const float* xr = x + (size_t)n * F;
    float s = sb[f];
    for (int i = 0; i < F; ++i) s += xr[i] * sW[i * 64 + f];
    h[idx] = s;
}

// ---------------- attention score precompute ----------------
__global__ __launch_bounds__(256) void score_ing_kernel(
    const float* __restrict__ h, float* __restrict__ s, int N,
    const float* __restrict__ a0, const float* __restrict__ a1,
    const float* __restrict__ a2)
{
    int idx = blockIdx.x * blockDim.x + threadIdx.x;  // n*4 + head
    if (idx >= N * 4) return;
    int n = idx >> 2, hh = idx & 3;
    const float* row = h + (size_t)n * 64 + hh * 16;
    float d0 = 0.f, d1 = 0.f, d2 = 0.f;
    for (int d = 0; d < 16; ++d) {
        float v = row[d];
        d0 += v * a0[hh * 16 + d];
        d1 += v * a1[hh * 16 + d];
        d2 += v * a2[hh * 16 + d];
    }
    float* sr = s + (size_t)n * 12;
    sr[0 + hh] = d0;
    sr[4 + hh] = d1;
    sr[8 + hh] = d2;
}

__global__ __launch_bounds__(256) void score_dir_kernel(
    const float* __restrict__ h, float* __restrict__ s, int N,
    const float* __restrict__ a0, const float* __restrict__ a1,
    const float* __restrict__ a2, const float* __restrict__ a3,
    const float* __restrict__ a4, const float* __restrict__ a5,
    const float* __restrict__ a6)
{
    int idx = blockIdx.x * blockDim.x + threadIdx.x;
    if (idx >= N * 4) return;
    int n = idx >> 2, hh = idx & 3;
    const float* row = h + (size_t)n * 64 + hh * 16;
    float d0 = 0.f, d1 = 0.f, d2 = 0.f, d3 = 0.f, d4 = 0.f, d5 = 0.f, d6 = 0.f;
    for (int d = 0; d < 16; ++d) {
        float v = row[d];
        d0 += v * a0[hh * 16 + d];
        d1 += v * a1[hh * 16 + d];
        d2 += v * a2[hh * 16 + d];
        d3 += v * a3[hh * 16 + d];
        d4 += v * a4[hh * 16 + d];
        d5 += v * a5[hh * 16 + d];
        d6 += v * a6[hh * 16 + d];
    }
    float* sr = s + (size_t)n * 28;
    sr[0  + hh] = d0;
    sr[4  + hh] = d1;
    sr[8  + hh] = d2;
    sr[12 + hh] = d3;
    sr[16 + hh] = d4;
    sr[20 + hh] = d5;
    sr[24 + hh] = d6;
}

// ---------------- CSR build: histogram of dst ----------------
__global__ __launch_bounds__(256) void hist_kernel(
    const int* __restrict__ ei, int* __restrict__ cnt)
{
    int e = blockIdx.x * blockDim.x + threadIdx.x;
    if (e >= NE) return;
    atomicAdd(&cnt[ei[NE + e]], 1);
}

// ---------------- CSR build: segment offsets (order-free reservation) ------
__global__ __launch_bounds__(256) void offsets_kernel(
    const int* __restrict__ cnt, int* __restrict__ start,
    int* __restrict__ ptr, int n, int* __restrict__ cursor)
{
    __shared__ int sh[256];
    __shared__ int base;
    int i = blockIdx.x * 256 + threadIdx.x;
    int c = (i < n) ? cnt[i] : 0;
    sh[threadIdx.x] = c;
    __syncthreads();
    for (int off = 1; off < 256; off <<= 1) {
        int v = (threadIdx.x >= off) ? sh[threadIdx.x - off] : 0;
        __syncthreads();
        sh[threadIdx.x] += v;
        __syncthreads();
    }
    if (threadIdx.x == 255) base = atomicAdd(cursor, sh[255]);
    __syncthreads();
    if (i < n) {
        int s = base + sh[threadIdx.x] - c;  // exclusive
        start[i] = s;
        ptr[i] = s;
    }
}

// ---------------- CSR build: scatter src into dst-grouped perm -------------
__global__ __launch_bounds__(256) void scatter_kernel(
    const int* __restrict__ ei, int* __restrict__ ptr, int* __restrict__ perm)
{
    int e = blockIdx.x * blockDim.x + threadIdx.x;
    if (e >= NE) return;
    int pos = atomicAdd(&ptr[ei[NE + e]], 1);
    perm[pos] = ei[e];
}

// ---------------- fused per-dst aggregation + softmax + relu + reduces -----
// one wave per dst node; zero float atomics in the edge loop
__global__ __launch_bounds__(256) void agg_kernel(
    const int* __restrict__ perm,
    const int* __restrict__ start, const int* __restrict__ endp,
    const float* __restrict__ h_src,
    const float* __restrict__ s_src, int ss, int soff,
    const float* __restrict__ s_dst, int ds, int doff,
    int ndst,
    const float* __restrict__ Wk, const float* __restrict__ bk,
    float* __restrict__ pool_out, float* __restrict__ sem_out)
{
    __shared__ float sWk[64 * 64];
    __shared__ float srow[4][64];
    __shared__ float sred[4][64];
    const int t = threadIdx.x & 63, w = threadIdx.x >> 6, h = t >> 4;
    if (sem_out) {
        for (int i = threadIdx.x; i < 4096; i += 256) sWk[i] = Wk[i];
    }
    float bkf = sem_out ? bk[t] : 0.f;
    float pool = 0.f, sem = 0.f;
    __syncthreads();
    int nwaves = gridDim.x * 4;
    for (int d = blockIdx.x * 4 + w; d < ndst; d += nwaves) {
        float adst = s_dst[(size_t)d * ds + doff + h];
        int jb = start[d], je = endp[d];
        float accf = 0.f, dsum = 0.f;
        for (int j = jb; j < je; ++j) {
            int src = perm[j];                               // wave-broadcast
            float a = s_src[(size_t)src * ss + soff + h] + adst;
            a = a > 0.f ? a : 0.2f * a;                      // leaky_relu(0.2)
            float ex = __expf(a);                            // no shift: |a| O(1)
            dsum += ex;
            accf += h_src[(size_t)src * 64 + t] * ex;        // coalesced 256B
        }
        float v = fmaxf(accf / (dsum + 1e-16f), 0.f);
        pool += v;
        if (sem_out) {
            srow[w][t] = v;                                   // wave-local LDS
            float a2 = bkf;
#pragma unroll
            for (int k = 0; k < 64; ++k) a2 += srow[w][k] * sWk[k * 64 + t];
            sem += tanhf(a2);
        }
    }
    sred[w][t] = pool;
    __syncthreads();
    if (w == 0)
        atomicAdd(&pool_out[t], sred[0][t] + sred[1][t] + sred[2][t] + sred[3][t]);
    if (sem_out) {
        __syncthreads();
        sred[w][t] = sem;
        __syncthreads();
        if (w == 0)
            atomicAdd(&sem_out[t], sred[0][t] + sred[1][t] + sred[2][t] + sred[3][t]);
    }
}

// ---------------- final: semantic softmax + pools + VAE head ----------------
__global__ __launch_bounds__(64) void final_kernel(
    const float* __restrict__ pool_ing, const float* __restrict__ pool_dir,
    const float* __restrict__ sem_dir, const float* __restrict__ q,
    const float* __restrict__ cond, const float* __restrict__ eps,
    const float* __restrict__ W_mu, const float* __restrict__ b_mu,
    const float* __restrict__ W_lv, const float* __restrict__ b_lv,
    const float* __restrict__ W_fc3, const float* __restrict__ b_fc3,
    const float* __restrict__ W_fc2, const float* __restrict__ b_fc2,
    float* __restrict__ out)
{
    __shared__ float gr[136];
    __shared__ float sc[4], attn[4];
    __shared__ float z[32], hfc[64];
    int t = threadIdx.x;  // 64 threads
    if (t < 4) {
        float s = 0.f;
        for (int f = 0; f < 64; ++f)
            s += (sem_dir[t * 64 + f] / (float)N_DIR) * q[f];
        sc[t] = s;
    }
    gr[t] = pool_ing[t] / (float)N_ING;   // out_ing == o_cont (T=1 softmax)
    __syncthreads();
    if (t == 0) {
        float m = fmaxf(fmaxf(sc[0], sc[1]), fmaxf(sc[2], sc[3]));
        float ssum = 0.f;
        for (int i = 0; i < 4; ++i) { attn[i] = expf(sc[i] - m); ssum += attn[i]; }
        for (int i = 0; i < 4; ++i) attn[i] /= ssum;
    }
    __syncthreads();
    {
        float v = 0.f;
        for (int tt = 0; tt < 4; ++tt)
            v += attn[tt] * (pool_dir[tt * 64 + t] / (float)N_DIR);
        gr[64 + t] = v;
    }
    if (t < 8) gr[128 + t] = cond[t];
    __syncthreads();
    if (t < 32) {
        float m = b_mu[t], lv = b_lv[t];
        for (int i = 0; i < 136; ++i) {
            float g = gr[i];
            m  += g * W_mu[i * 32 + t];
            lv += g * W_lv[i * 32 + t];
        }
        out[16 + t] = m;
        out[48 + t] = lv;
        z[t] = m + eps[t] * expf(0.5f * lv);
    }
    __syncthreads();
    {
        float v = b_fc3[t];
        for (int j = 0; j < 32; ++j) v += z[j] * W_fc3[j * 64 + t];
        hfc[t] = fmaxf(v, 0.f);
    }
    __syncthreads();
    if (t < 16) {
        float v = b_fc2[t];
        for (int f = 0; f < 64; ++f) v += hfc[f] * W_fc2[f * 16 + t];
        out[t] = tanhf(v);
    }
}

extern "C" void kernel_launch(void* const* d_in, const int* in_sizes, int n_in,
                              void* d_out, int out_size, void* d_ws, size_t ws_size,
                              hipStream_t stream) {
    const float* x_ing = (const float*)d_in[0];
    const float* x_dir = (const float*)d_in[1];
    const float* cond  = (const float*)d_in[2];
    const float* eps   = (const float*)d_in[3];
    const int* ei_cooc     = (const int*)d_in[4];
    const int* ei_used     = (const int*)d_in[5];
    const int* ei_contains = (const int*)d_in[6];
    const int* ei_pairs    = (const int*)d_in[7];
    const int* ei_follows  = (const int*)d_in[8];
    const float* W_pi = (const float*)d_in[9];
    const float* b_pi = (const float*)d_in[10];
    const float* W_pd = (const float*)d_in[11];
    const float* b_pd = (const float*)d_in[12];
    const float* Wk   = (const float*)d_in[13];
    const float* bk   = (const float*)d_in[14];
    const float* q    = (const float*)d_in[15];
    const float* W_mu = (const float*)d_in[16];
    const float* b_mu = (const float*)d_in[17];
    const float* W_lv = (const float*)d_in[18];
    const float* b_lv = (const float*)d_in[19];
    const float* W_fc3 = (const float*)d_in[20];
    const float* b_fc3 = (const float*)d_in[21];
    const float* W_fc2 = (const float*)d_in[22];
    const float* b_fc2 = (const float*)d_in[23];
    const float* as_cooc     = (const float*)d_in[24];
    const float* ad_cooc     = (const float*)d_in[25];
    const float* as_used     = (const float*)d_in[26];
    const float* ad_used     = (const float*)d_in[27];
    const float* as_contains = (const float*)d_in[28];
    const float* ad_contains = (const float*)d_in[29];
    const float* as_pairs    = (const float*)d_in[30];
    const float* ad_pairs    = (const float*)d_in[31];
    const float* as_follows  = (const float*)d_in[32];
    const float* ad_follows  = (const float*)d_in[33];

    // ---- workspace layout ----
    float* ws = (float*)d_ws;
    float* h_ing = ws;                          // 6.4M floats
    float* h_dir = h_ing + (size_t)N_ING * 64;  // 3.2M
    float* s_ing = h_dir + (size_t)N_DIR * 64;  // 1.2M   [N_ING][3][4]
    float* s_dir = s_ing + (size_t)N_ING * 12;  // 1.4M   [N_DIR][7][4]
    int*   perm  = (int*)(s_dir + (size_t)N_DIR * 28);  // 5M ints
    int*   start = perm + (size_t)5 * NE;       // 300K
    int*   ptr   = start + NDST_TOTAL;          // 300K
    int*   cnt   = ptr + NDST_TOTAL;            // 300K  (zeroed region begins here)
    int*   cursor = cnt + NDST_TOTAL;           // 1
    float* pool_ing = (float*)(cursor + 1);     // 64
    float* pool_dir = pool_ing + 64;            // 4*64
    float* sem_dir  = pool_dir + 256;           // 4*64

    // single memset: cnt + cursor + pools (contiguous)
    hipMemsetAsync(cnt, 0, (size_t)(NDST_TOTAL + 1 + 64 + 256 + 256) * sizeof(int), stream);

    // projections + per-node attention scores
    proj_kernel<<<(N_ING * 64) / 256, 256, 0, stream>>>(x_ing, W_pi, b_pi, h_ing, N_ING, 16);
    proj_kernel<<<(N_DIR * 64) / 256, 256, 0, stream>>>(x_dir, W_pd, b_pd, h_dir, N_DIR, 8);
    // ing slots: 0 = src(cooc), 1 = src(used), 2 = dst(contains)
    score_ing_kernel<<<(N_ING * 4 + 255) / 256, 256, 0, stream>>>(
        h_ing, s_ing, N_ING, as_cooc, as_used, ad_contains);
    // dir slots: 0 = dst(cooc), 1 = dst(used), 2 = src(contains),
    //            3 = src(pairs), 4 = dst(pairs), 5 = src(follows), 6 = dst(follows)
    score_dir_kernel<<<(N_DIR * 4 + 255) / 256, 256, 0, stream>>>(
        h_dir, s_dir, N_DIR, ad_cooc, ad_used, as_contains, as_pairs, ad_pairs,
        as_follows, ad_follows);

    // dst-space bases in the combined CSR arrays
    // 0:cooc(dir) 1:used(dir) 2:contains(ing) 3:pairs(dir) 4:follows(dir)
    const int   base[5] = { 0, 50000, 100000, 200000, 250000 };
    const int   nd[5]   = { N_DIR, N_DIR, N_ING, N_DIR, N_DIR };
    const int*  eis[5]  = { ei_cooc, ei_used, ei_contains, ei_pairs, ei_follows };

    const int EB = (NE + 255) / 256;
    for (int tix = 0; tix < 5; ++tix)
        hist_kernel<<<EB, 256, 0, stream>>>(eis[tix], cnt + base[tix]);
    offsets_kernel<<<(NDST_TOTAL + 255) / 256, 256, 0, stream>>>(
        cnt, start, ptr, NDST_TOTAL, cursor);
    for (int tix = 0; tix < 5; ++tix)
        scatter_kernel<<<EB, 256, 0, stream>>>(eis[tix], ptr + base[tix], perm);

    struct AggP {
        const float* hsrc;
        const float* ssrc; int ss, soff;
        const float* sdst; int ds, doff;
        int dir_slot;  // -1 => ingredient-dst (contains)
    };
    AggP ap[5] = {
        { h_ing, s_ing, 12, 0,  s_dir, 28, 0,   0 },  // cooc
        { h_ing, s_ing, 12, 4,  s_dir, 28, 4,   1 },  // used
        { h_dir, s_dir, 28, 8,  s_ing, 12, 8,  -1 },  // contains
        { h_dir, s_dir, 28, 12, s_dir, 28, 16,  2 },  // pairs
        { h_dir, s_dir, 28, 20, s_dir, 28, 24,  3 },  // follows
    };
    for (int tix = 0; tix < 5; ++tix) {
        AggP& p = ap[tix];
        float* pout = (p.dir_slot < 0) ? pool_ing : pool_dir + p.dir_slot * 64;
        float* sout = (p.dir_slot < 0) ? nullptr  : sem_dir  + p.dir_slot * 64;
        agg_kernel<<<2048, 256, 0, stream>>>(
            perm, start + base[tix], ptr + base[tix],
            p.hsrc, p.ssrc, p.ss, p.soff, p.sdst, p.ds, p.doff,
            nd[tix], Wk, bk, pout, sout);
    }

    final_kernel<<<1, 64, 0, stream>>>(
        pool_ing, pool_dir, sem_dir, q, cond, eps,
        W_mu, b_mu, W_lv, b_lv, W_fc3, b_fc3, W_fc2, b_fc2, (float*)d_out);
}

// Round 3
// 1251.639 us; speedup vs baseline: 2.1355x; 1.1142x over previous
//
#include <hip/hip_runtime.h>
#include <math.h>

#define N_ING 100000
#define N_DIR 50000
#define NE    1000000
#define NDST_TOTAL 300000   // 50K(cooc)+50K(used)+100K(contains)+50K(pairs)+50K(follows)

// ---------------- projection: h = x @ W + b ----------------
__global__ __launch_bounds__(256) void proj_kernel(
    const float* __restrict__ x, const float* __restrict__ W,
    const float* __restrict__ b, float* __restrict__ h, int N, int F)
{
    __shared__ float sW[16 * 64];
    __shared__ float sb[64];
    for (int i = threadIdx.x; i < F * 64; i += blockDim.x) sW[i] = W[i];
    if (threadIdx.x < 64) sb[threadIdx.x] = b[threadIdx.x];
    __syncthreads();
    int idx = blockIdx.x * blockDim.x + threadIdx.x;
    if (idx >= N * 64) return;
    int n = idx >> 6, f = idx & 63;
    const float* xr = x + (size_t)n * F;
    float s = sb[f];
    for (int i = 0; i < F; ++i) s += xr[i] * sW[i * 64 + f];
    h[idx] = s;
}

// ---------------- attention score precompute ----------------
__global__ __launch_bounds__(256) void score_ing_kernel(
    const float* __restrict__ h, float* __restrict__ s, int N,
    const float* __restrict__ a0, const float* __restrict__ a1,
    const float* __restrict__ a2)
{
    int idx = blockIdx.x * blockDim.x + threadIdx.x;  // n*4 + head
    if (idx >= N * 4) return;
    int n = idx >> 2, hh = idx & 3;
    const float* row = h + (size_t)n * 64 + hh * 16;
    float d0 = 0.f, d1 = 0.f, d2 = 0.f;
    for (int d = 0; d < 16; ++d) {
        float v = row[d];
        d0 += v * a0[hh * 16 + d];
        d1 += v * a1[hh * 16 + d];
        d2 += v * a2[hh * 16 + d];
    }
    float* sr = s + (size_t)n * 12;
    sr[0 + hh] = d0;
    sr[4 + hh] = d1;
    sr[8 + hh] = d2;
}

__global__ __launch_bounds__(256) void score_dir_kernel(
    const float* __restrict__ h, float* __restrict__ s, int N,
    const float* __restrict__ a0, const float* __restrict__ a1,
    const float* __restrict__ a2, const float* __restrict__ a3,
    const float* __restrict__ a4, const float* __restrict__ a5,
    const float* __restrict__ a6)
{
    int idx = blockIdx.x * blockDim.x + threadIdx.x;
    if (idx >= N * 4) return;
    int n = idx >> 2, hh = idx & 3;
    const float* row = h + (size_t)n * 64 + hh * 16;
    float d0 = 0.f, d1 = 0.f, d2 = 0.f, d3 = 0.f, d4 = 0.f, d5 = 0.f, d6 = 0.f;
    for (int d = 0; d < 16; ++d) {
        float v = row[d];
        d0 += v * a0[hh * 16 + d];
        d1 += v * a1[hh * 16 + d];
        d2 += v * a2[hh * 16 + d];
        d3 += v * a3[hh * 16 + d];
        d4 += v * a4[hh * 16 + d];
        d5 += v * a5[hh * 16 + d];
        d6 += v * a6[hh * 16 + d];
    }
    float* sr = s + (size_t)n * 28;
    sr[0  + hh] = d0;
    sr[4  + hh] = d1;
    sr[8  + hh] = d2;
    sr[12 + hh] = d3;
    sr[16 + hh] = d4;
    sr[20 + hh] = d5;
    sr[24 + hh] = d6;
}

// ---------------- CSR build: combined histogram, 4 edges/thread ------------
#define BPT 977   // blocks per type: 977*256*4 >= 1M
__global__ __launch_bounds__(256) void hist5_kernel(
    const int* __restrict__ e0, const int* __restrict__ e1,
    const int* __restrict__ e2, const int* __restrict__ e3,
    const int* __restrict__ e4, int* __restrict__ cnt)
{
    const int type = blockIdx.x / BPT;
    const int* ei = type == 0 ? e0 : type == 1 ? e1 : type == 2 ? e2
                  : type == 3 ? e3 : e4;
    const int b = type == 0 ? 0 : type == 1 ? 50000 : type == 2 ? 100000
                : type == 3 ? 200000 : 250000;
    int e = ((blockIdx.x % BPT) * 256 + threadIdx.x) * 4;
    if (e + 3 < NE) {
        int4 d = *(const int4*)&ei[NE + e];
        atomicAdd(&cnt[b + d.x], 1);
        atomicAdd(&cnt[b + d.y], 1);
        atomicAdd(&cnt[b + d.z], 1);
        atomicAdd(&cnt[b + d.w], 1);
    } else {
        for (; e < NE; ++e) atomicAdd(&cnt[b + ei[NE + e]], 1);
    }
}

// ---------------- CSR build: segment offsets (order-free reservation) ------
__global__ __launch_bounds__(256) void offsets_kernel(
    const int* __restrict__ cnt, int* __restrict__ start,
    int* __restrict__ ptr, int n, int* __restrict__ cursor)
{
    __shared__ int sh[256];
    __shared__ int base;
    int i = blockIdx.x * 256 + threadIdx.x;
    int c = (i < n) ? cnt[i] : 0;
    sh[threadIdx.x] = c;
    __syncthreads();
    for (int off = 1; off < 256; off <<= 1) {
        int v = (threadIdx.x >= off) ? sh[threadIdx.x - off] : 0;
        __syncthreads();
        sh[threadIdx.x] += v;
        __syncthreads();
    }
    if (threadIdx.x == 255) base = atomicAdd(cursor, sh[255]);
    __syncthreads();
    if (i < n) {
        int s = base + sh[threadIdx.x] - c;  // exclusive
        start[i] = s;
        ptr[i] = s;
    }
}

// ---------------- CSR build: combined scatter, 4 edges/thread --------------
__global__ __launch_bounds__(256) void scatter5_kernel(
    const int* __restrict__ e0, const int* __restrict__ e1,
    const int* __restrict__ e2, const int* __restrict__ e3,
    const int* __restrict__ e4, int* __restrict__ ptr, int* __restrict__ perm)
{
    const int type = blockIdx.x / BPT;
    const int* ei = type == 0 ? e0 : type == 1 ? e1 : type == 2 ? e2
                  : type == 3 ? e3 : e4;
    const int b = type == 0 ? 0 : type == 1 ? 50000 : type == 2 ? 100000
                : type == 3 ? 200000 : 250000;
    int e = ((blockIdx.x % BPT) * 256 + threadIdx.x) * 4;
    if (e + 3 < NE) {
        int4 s = *(const int4*)&ei[e];
        int4 d = *(const int4*)&ei[NE + e];
        int p0 = atomicAdd(&ptr[b + d.x], 1);
        int p1 = atomicAdd(&ptr[b + d.y], 1);
        int p2 = atomicAdd(&ptr[b + d.z], 1);
        int p3 = atomicAdd(&ptr[b + d.w], 1);
        perm[p0] = s.x;
        perm[p1] = s.y;
        perm[p2] = s.z;
        perm[p3] = s.w;
    } else {
        for (; e < NE; ++e) {
            int pos = atomicAdd(&ptr[b + ei[NE + e]], 1);
            perm[pos] = ei[e];
        }
    }
}

// ---------------- fused per-dst aggregation + softmax + relu + reduces -----
// one wave per dst node; zero float atomics; 4-wide unrolled gather pipeline
__global__ __launch_bounds__(256) void agg_kernel(
    const int* __restrict__ perm,
    const int* __restrict__ start, const int* __restrict__ endp,
    const float* __restrict__ h_src,
    const float* __restrict__ s_src, int ss, int soff,
    const float* __restrict__ s_dst, int ds, int doff,
    int ndst,
    const float* __restrict__ Wk, const float* __restrict__ bk,
    float* __restrict__ pool_out, float* __restrict__ sem_out)
{
    __shared__ float sWk[64 * 64];
    __shared__ float srow[4][64];
    __shared__ float sred[4][64];
    const int t = threadIdx.x & 63, w = threadIdx.x >> 6, h = t >> 4;
    if (sem_out) {
        for (int i = threadIdx.x; i < 4096; i += 256) sWk[i] = Wk[i];
    }
    float bkf = sem_out ? bk[t] : 0.f;
    float pool = 0.f, sem = 0.f;
    __syncthreads();
    int nwaves = gridDim.x * 4;
    for (int d = blockIdx.x * 4 + w; d < ndst; d += nwaves) {
        float adst = s_dst[(size_t)d * ds + doff + h];
        int jb = start[d], je = endp[d];
        float accf = 0.f, dsum = 0.f;
        int j = jb;
        for (; j + 4 <= je; j += 4) {
            // 4 independent src indices in flight
            int s0 = perm[j], s1 = perm[j + 1], s2 = perm[j + 2], s3 = perm[j + 3];
            // 8 independent gathers in flight
            float c0 = s_src[(size_t)s0 * ss + soff + h];
            float c1 = s_src[(size_t)s1 * ss + soff + h];
            float c2 = s_src[(size_t)s2 * ss + soff + h];
            float c3 = s_src[(size_t)s3 * ss + soff + h];
            float g0 = h_src[(size_t)s0 * 64 + t];
            float g1 = h_src[(size_t)s1 * 64 + t];
            float g2 = h_src[(size_t)s2 * 64 + t];
            float g3 = h_src[(size_t)s3 * 64 + t];
            float a0 = c0 + adst; a0 = a0 > 0.f ? a0 : 0.2f * a0;
            float a1 = c1 + adst; a1 = a1 > 0.f ? a1 : 0.2f * a1;
            float a2 = c2 + adst; a2 = a2 > 0.f ? a2 : 0.2f * a2;
            float a3 = c3 + adst; a3 = a3 > 0.f ? a3 : 0.2f * a3;
            float e0 = __expf(a0), e1 = __expf(a1), e2 = __expf(a2), e3 = __expf(a3);
            dsum += (e0 + e1) + (e2 + e3);
            accf += g0 * e0 + g1 * e1 + g2 * e2 + g3 * e3;
        }
        for (; j < je; ++j) {
            int src = perm[j];
            float a = s_src[(size_t)src * ss + soff + h] + adst;
            a = a > 0.f ? a : 0.2f * a;
            float ex = __expf(a);
            dsum += ex;
            accf += h_src[(size_t)src * 64 + t] * ex;
        }
        float v = fmaxf(accf / (dsum + 1e-16f), 0.f);
        pool += v;
        if (sem_out) {
            srow[w][t] = v;                                   // wave-local LDS
            float a2 = bkf;
#pragma unroll
            for (int k = 0; k < 64; ++k) a2 += srow[w][k] * sWk[k * 64 + t];
            sem += tanhf(a2);
        }
    }
    sred[w][t] = pool;
    __syncthreads();
    if (w == 0)
        atomicAdd(&pool_out[t], sred[0][t] + sred[1][t] + sred[2][t] + sred[3][t]);
    if (sem_out) {
        __syncthreads();
        sred[w][t] = sem;
        __syncthreads();
        if (w == 0)
            atomicAdd(&sem_out[t], sred[0][t] + sred[1][t] + sred[2][t] + sred[3][t]);
    }
}

// ---------------- final: semantic softmax + pools + VAE head ----------------
__global__ __launch_bounds__(64) void final_kernel(
    const float* __restrict__ pool_ing, const float* __restrict__ pool_dir,
    const float* __restrict__ sem_dir, const float* __restrict__ q,
    const float* __restrict__ cond, const float* __restrict__ eps,
    const float* __restrict__ W_mu, const float* __restrict__ b_mu,
    const float* __restrict__ W_lv, const float* __restrict__ b_lv,
    const float* __restrict__ W_fc3, const float* __restrict__ b_fc3,
    const float* __restrict__ W_fc2, const float* __restrict__ b_fc2,
    float* __restrict__ out)
{
    __shared__ float gr[136];
    __shared__ float sc[4], attn[4];
    __shared__ float z[32], hfc[64];
    int t = threadIdx.x;  // 64 threads
    if (t < 4) {
        float s = 0.f;
        for (int f = 0; f < 64; ++f)
            s += (sem_dir[t * 64 + f] / (float)N_DIR) * q[f];
        sc[t] = s;
    }
    gr[t] = pool_ing[t] / (float)N_ING;   // out_ing == o_cont (T=1 softmax)
    __syncthreads();
    if (t == 0) {
        float m = fmaxf(fmaxf(sc[0], sc[1]), fmaxf(sc[2], sc[3]));
        float ssum = 0.f;
        for (int i = 0; i < 4; ++i) { attn[i] = expf(sc[i] - m); ssum += attn[i]; }
        for (int i = 0; i < 4; ++i) attn[i] /= ssum;
    }
    __syncthreads();
    {
        float v = 0.f;
        for (int tt = 0; tt < 4; ++tt)
            v += attn[tt] * (pool_dir[tt * 64 + t] / (float)N_DIR);
        gr[64 + t] = v;
    }
    if (t < 8) gr[128 + t] = cond[t];
    __syncthreads();
    if (t < 32) {
        float m = b_mu[t], lv = b_lv[t];
        for (int i = 0; i < 136; ++i) {
            float g = gr[i];
            m  += g * W_mu[i * 32 + t];
            lv += g * W_lv[i * 32 + t];
        }
        out[16 + t] = m;
        out[48 + t] = lv;
        z[t] = m + eps[t] * expf(0.5f * lv);
    }
    __syncthreads();
    {
        float v = b_fc3[t];
        for (int j = 0; j < 32; ++j) v += z[j] * W_fc3[j * 64 + t];
        hfc[t] = fmaxf(v, 0.f);
    }
    __syncthreads();
    if (t < 16) {
        float v = b_fc2[t];
        for (int f = 0; f < 64; ++f) v += hfc[f] * W_fc2[f * 16 + t];
        out[t] = tanhf(v);
    }
}

extern "C" void kernel_launch(void* const* d_in, const int* in_sizes, int n_in,
                              void* d_out, int out_size, void* d_ws, size_t ws_size,
                              hipStream_t stream) {
    const float* x_ing = (const float*)d_in[0];
    const float* x_dir = (const float*)d_in[1];
    const float* cond  = (const float*)d_in[2];
    const float* eps   = (const float*)d_in[3];
    const int* ei_cooc     = (const int*)d_in[4];
    const int* ei_used     = (const int*)d_in[5];
    const int* ei_contains = (const int*)d_in[6];
    const int* ei_pairs    = (const int*)d_in[7];
    const int* ei_follows  = (const int*)d_in[8];
    const float* W_pi = (const float*)d_in[9];
    const float* b_pi = (const float*)d_in[10];
    const float* W_pd = (const float*)d_in[11];
    const float* b_pd = (const float*)d_in[12];
    const float* Wk   = (const float*)d_in[13];
    const float* bk   = (const float*)d_in[14];
    const float* q    = (const float*)d_in[15];
    const float* W_mu = (const float*)d_in[16];
    const float* b_mu = (const float*)d_in[17];
    const float* W_lv = (const float*)d_in[18];
    const float* b_lv = (const float*)d_in[19];
    const float* W_fc3 = (const float*)d_in[20];
    const float* b_fc3 = (const float*)d_in[21];
    const float* W_fc2 = (const float*)d_in[22];
    const float* b_fc2 = (const float*)d_in[23];
    const float* as_cooc     = (const float*)d_in[24];
    const float* ad_cooc     = (const float*)d_in[25];
    const float* as_used     = (const float*)d_in[26];
    const float* ad_used     = (const float*)d_in[27];
    const float* as_contains = (const float*)d_in[28];
    const float* ad_contains = (const float*)d_in[29];
    const float* as_pairs    = (const float*)d_in[30];
    const float* ad_pairs    = (const float*)d_in[31];
    const float* as_follows  = (const float*)d_in[32];
    const float* ad_follows  = (const float*)d_in[33];

    // ---- workspace layout ----
    float* ws = (float*)d_ws;
    float* h_ing = ws;                          // 6.4M floats
    float* h_dir = h_ing + (size_t)N_ING * 64;  // 3.2M
    float* s_ing = h_dir + (size_t)N_DIR * 64;  // 1.2M   [N_ING][3][4]
    float* s_dir = s_ing + (size_t)N_ING * 12;  // 1.4M   [N_DIR][7][4]
    int*   perm  = (int*)(s_dir + (size_t)N_DIR * 28);  // 5M ints
    int*   start = perm + (size_t)5 * NE;       // 300K
    int*   ptr   = start + NDST_TOTAL;          // 300K
    int*   cnt   = ptr + NDST_TOTAL;            // 300K  (zeroed region begins here)
    int*   cursor = cnt + NDST_TOTAL;           // 1
    float* pool_ing = (float*)(cursor + 1);     // 64
    float* pool_dir = pool_ing + 64;            // 4*64
    float* sem_dir  = pool_dir + 256;           // 4*64

    // single memset: cnt + cursor + pools (contiguous)
    hipMemsetAsync(cnt, 0, (size_t)(NDST_TOTAL + 1 + 64 + 256 + 256) * sizeof(int), stream);

    // projections + per-node attention scores
    proj_kernel<<<(N_ING * 64) / 256, 256, 0, stream>>>(x_ing, W_pi, b_pi, h_ing, N_ING, 16);
    proj_kernel<<<(N_DIR * 64) / 256, 256, 0, stream>>>(x_dir, W_pd, b_pd, h_dir, N_DIR, 8);
    // ing slots: 0 = src(cooc), 1 = src(used), 2 = dst(contains)
    score_ing_kernel<<<(N_ING * 4 + 255) / 256, 256, 0, stream>>>(
        h_ing, s_ing, N_ING, as_cooc, as_used, ad_contains);
    // dir slots: 0 = dst(cooc), 1 = dst(used), 2 = src(contains),
    //            3 = src(pairs), 4 = dst(pairs), 5 = src(follows), 6 = dst(follows)
    score_dir_kernel<<<(N_DIR * 4 + 255) / 256, 256, 0, stream>>>(
        h_dir, s_dir, N_DIR, ad_cooc, ad_used, as_contains, as_pairs, ad_pairs,
        as_follows, ad_follows);

    // combined CSR build across all 5 types
    hist5_kernel<<<5 * BPT, 256, 0, stream>>>(
        ei_cooc, ei_used, ei_contains, ei_pairs, ei_follows, cnt);
    offsets_kernel<<<(NDST_TOTAL + 255) / 256, 256, 0, stream>>>(
        cnt, start, ptr, NDST_TOTAL, cursor);
    scatter5_kernel<<<5 * BPT, 256, 0, stream>>>(
        ei_cooc, ei_used, ei_contains, ei_pairs, ei_follows, ptr, perm);

    // dst-space bases: 0:cooc(dir) 1:used(dir) 2:contains(ing) 3:pairs(dir) 4:follows(dir)
    const int base[5] = { 0, 50000, 100000, 200000, 250000 };
    const int nd[5]   = { N_DIR, N_DIR, N_ING, N_DIR, N_DIR };

    struct AggP {
        const float* hsrc;
        const float* ssrc; int ss, soff;
        const float* sdst; int ds, doff;
        int dir_slot;  // -1 => ingredient-dst (contains)
    };
    AggP ap[5] = {
        { h_ing, s_ing, 12, 0,  s_dir, 28, 0,   0 },  // cooc
        { h_ing, s_ing, 12, 4,  s_dir, 28, 4,   1 },  // used
        { h_dir, s_dir, 28, 8,  s_ing, 12, 8,  -1 },  // contains
        { h_dir, s_dir, 28, 12, s_dir, 28, 16,  2 },  // pairs
        { h_dir, s_dir, 28, 20, s_dir, 28, 24,  3 },  // follows
    };
    for (int tix = 0; tix < 5; ++tix) {
        AggP& p = ap[tix];
        float* pout = (p.dir_slot < 0) ? pool_ing : pool_dir + p.dir_slot * 64;
        float* sout = (p.dir_slot < 0) ? nullptr  : sem_dir  + p.dir_slot * 64;
        agg_kernel<<<2048, 256, 0, stream>>>(
            perm, start + base[tix], ptr + base[tix],
            p.hsrc, p.ssrc, p.ss, p.soff, p.sdst, p.ds, p.doff,
            nd[tix], Wk, bk, pout, sout);
    }

    final_kernel<<<1, 64, 0, stream>>>(
        pool_ing, pool_dir, sem_dir, q, cond, eps,
        W_mu, b_mu, W_lv, b_lv, W_fc3, b_fc3, W_fc2, b_fc2, (float*)d_out);
}

// Round 4
// 805.438 us; speedup vs baseline: 3.3185x; 1.5540x over previous
//
#include <hip/hip_runtime.h>
#include <math.h>

#define N_ING 100000
#define N_DIR 50000
#define NE    1000000
#define NDST_TOTAL 300000   // 50K(cooc)+50K(used)+100K(contains)+50K(pairs)+50K(follows)

// ---------------- projection: h = x @ W + b ----------------
__global__ __launch_bounds__(256) void proj_kernel(
    const float* __restrict__ x, const float* __restrict__ W,
    const float* __restrict__ b, float* __restrict__ h, int N, int F)
{
    __shared__ float sW[16 * 64];
    __shared__ float sb[64];
    for (int i = threadIdx.x; i < F * 64; i += blockDim.x) sW[i] = W[i];
    if (threadIdx.x < 64) sb[threadIdx.x] = b[threadIdx.x];
    __syncthreads();
    int idx = blockIdx.x * blockDim.x + threadIdx.x;
    if (idx >= N * 64) return;
    int n = idx >> 6, f = idx & 63;
    const float* xr = x + (size_t)n * F;
    float s = sb[f];
    for (int i = 0; i < F; ++i) s += xr[i] * sW[i * 64 + f];
    h[idx] = s;
}

// ---------------- attention score precompute ----------------
__global__ __launch_bounds__(256) void score_ing_kernel(
    const float* __restrict__ h, float* __restrict__ s, int N,
    const float* __restrict__ a0, const float* __restrict__ a1,
    const float* __restrict__ a2)
{
    int idx = blockIdx.x * blockDim.x + threadIdx.x;  // n*4 + head
    if (idx >= N * 4) return;
    int n = idx >> 2, hh = idx & 3;
    const float* row = h + (size_t)n * 64 + hh * 16;
    float d0 = 0.f, d1 = 0.f, d2 = 0.f;
    for (int d = 0; d < 16; ++d) {
        float v = row[d];
        d0 += v * a0[hh * 16 + d];
        d1 += v * a1[hh * 16 + d];
        d2 += v * a2[hh * 16 + d];
    }
    float* sr = s + (size_t)n * 12;
    sr[0 + hh] = d0;
    sr[4 + hh] = d1;
    sr[8 + hh] = d2;
}

__global__ __launch_bounds__(256) void score_dir_kernel(
    const float* __restrict__ h, float* __restrict__ s, int N,
    const float* __restrict__ a0, const float* __restrict__ a1,
    const float* __restrict__ a2, const float* __restrict__ a3,
    const float* __restrict__ a4, const float* __restrict__ a5,
    const float* __restrict__ a6)
{
    int idx = blockIdx.x * blockDim.x + threadIdx.x;
    if (idx >= N * 4) return;
    int n = idx >> 2, hh = idx & 3;
    const float* row = h + (size_t)n * 64 + hh * 16;
    float d0 = 0.f, d1 = 0.f, d2 = 0.f, d3 = 0.f, d4 = 0.f, d5 = 0.f, d6 = 0.f;
    for (int d = 0; d < 16; ++d) {
        float v = row[d];
        d0 += v * a0[hh * 16 + d];
        d1 += v * a1[hh * 16 + d];
        d2 += v * a2[hh * 16 + d];
        d3 += v * a3[hh * 16 + d];
        d4 += v * a4[hh * 16 + d];
        d5 += v * a5[hh * 16 + d];
        d6 += v * a6[hh * 16 + d];
    }
    float* sr = s + (size_t)n * 28;
    sr[0  + hh] = d0;
    sr[4  + hh] = d1;
    sr[8  + hh] = d2;
    sr[12 + hh] = d3;
    sr[16 + hh] = d4;
    sr[20 + hh] = d5;
    sr[24 + hh] = d6;
}

// ---------------- CSR pass 1: histogram + per-edge rank, 8 edges/thread ----
// atomic return feeds only a coalesced store (non-blocking)
#define BPT8 489   // 489*256*8 >= 1M
__global__ __launch_bounds__(256) void histrank5_kernel(
    const int* __restrict__ e0, const int* __restrict__ e1,
    const int* __restrict__ e2, const int* __restrict__ e3,
    const int* __restrict__ e4, int* __restrict__ cnt, int* __restrict__ rank)
{
    const int type = blockIdx.x / BPT8;
    const int* ei = type == 0 ? e0 : type == 1 ? e1 : type == 2 ? e2
                  : type == 3 ? e3 : e4;
    const int b = type == 0 ? 0 : type == 1 ? 50000 : type == 2 ? 100000
                : type == 3 ? 200000 : 250000;
    int e = ((blockIdx.x % BPT8) * 256 + threadIdx.x) * 8;
    if (e >= NE) return;
    int4 d0 = *(const int4*)&ei[NE + e];
    int4 d1 = *(const int4*)&ei[NE + e + 4];
    int r0 = atomicAdd(&cnt[b + d0.x], 1);
    int r1 = atomicAdd(&cnt[b + d0.y], 1);
    int r2 = atomicAdd(&cnt[b + d0.z], 1);
    int r3 = atomicAdd(&cnt[b + d0.w], 1);
    int r4 = atomicAdd(&cnt[b + d1.x], 1);
    int r5 = atomicAdd(&cnt[b + d1.y], 1);
    int r6 = atomicAdd(&cnt[b + d1.z], 1);
    int r7 = atomicAdd(&cnt[b + d1.w], 1);
    int* rp = &rank[(size_t)type * NE + e];
    *(int4*)rp       = make_int4(r0, r1, r2, r3);
    *(int4*)(rp + 4) = make_int4(r4, r5, r6, r7);
}

// ---------------- CSR pass 2: segment offsets (order-free reservation) -----
__global__ __launch_bounds__(256) void offsets_kernel(
    const int* __restrict__ cnt, int* __restrict__ start,
    int n, int* __restrict__ cursor)
{
    __shared__ int sh[256];
    __shared__ int base;
    int i = blockIdx.x * 256 + threadIdx.x;
    int c = (i < n) ? cnt[i] : 0;
    sh[threadIdx.x] = c;
    __syncthreads();
    for (int off = 1; off < 256; off <<= 1) {
        int v = (threadIdx.x >= off) ? sh[threadIdx.x - off] : 0;
        __syncthreads();
        sh[threadIdx.x] += v;
        __syncthreads();
    }
    if (threadIdx.x == 255) base = atomicAdd(cursor, sh[255]);
    __syncthreads();
    if (i < n) start[i] = base + sh[threadIdx.x] - c;  // exclusive
}

// ---------------- CSR pass 3: atomic-free scatter, 8 edges/thread ----------
__global__ __launch_bounds__(256) void scatterrank5_kernel(
    const int* __restrict__ e0, const int* __restrict__ e1,
    const int* __restrict__ e2, const int* __restrict__ e3,
    const int* __restrict__ e4, const int* __restrict__ start,
    const int* __restrict__ rank, int* __restrict__ perm)
{
    const int type = blockIdx.x / BPT8;
    const int* ei = type == 0 ? e0 : type == 1 ? e1 : type == 2 ? e2
                  : type == 3 ? e3 : e4;
    const int b = type == 0 ? 0 : type == 1 ? 50000 : type == 2 ? 100000
                : type == 3 ? 200000 : 250000;
    int e = ((blockIdx.x % BPT8) * 256 + threadIdx.x) * 8;
    if (e >= NE) return;
    int4 s0 = *(const int4*)&ei[e];
    int4 s1 = *(const int4*)&ei[e + 4];
    int4 d0 = *(const int4*)&ei[NE + e];
    int4 d1 = *(const int4*)&ei[NE + e + 4];
    const int* rp = &rank[(size_t)type * NE + e];
    int4 r0 = *(const int4*)rp;
    int4 r1 = *(const int4*)(rp + 4);
    // 8 independent L2-hot gathers of start[], then 8 independent writes
    int p0 = start[b + d0.x] + r0.x;
    int p1 = start[b + d0.y] + r0.y;
    int p2 = start[b + d0.z] + r0.z;
    int p3 = start[b + d0.w] + r0.w;
    int p4 = start[b + d1.x] + r1.x;
    int p5 = start[b + d1.y] + r1.y;
    int p6 = start[b + d1.z] + r1.z;
    int p7 = start[b + d1.w] + r1.w;
    perm[p0] = s0.x;
    perm[p1] = s0.y;
    perm[p2] = s0.z;
    perm[p3] = s0.w;
    perm[p4] = s1.x;
    perm[p5] = s1.y;
    perm[p6] = s1.z;
    perm[p7] = s1.w;
}

// ---------------- fused aggregation, ALL types in one dispatch -------------
// one wave per dst segment; zero float atomics; 4-wide gather pipeline
__global__ __launch_bounds__(256) void agg_all_kernel(
    const int* __restrict__ perm, const int* __restrict__ start,
    const int* __restrict__ cnt,
    const float* __restrict__ h_ing, const float* __restrict__ h_dir,
    const float* __restrict__ s_ing, const float* __restrict__ s_dir,
    const float* __restrict__ Wk, const float* __restrict__ bk,
    float* __restrict__ pool_ing, float* __restrict__ pool_dir,
    float* __restrict__ sem_dir)
{
    __shared__ float sWk[64 * 64];
    __shared__ float srow[4][64];
    __shared__ float sred[4][64];
    const int t = threadIdx.x & 63, w = threadIdx.x >> 6, h = t >> 4;
    for (int i = threadIdx.x; i < 4096; i += 256) sWk[i] = Wk[i];
    const float bkf = bk[t];
    float p_ing = 0.f;
    float p0 = 0.f, p1 = 0.f, p2 = 0.f, p3 = 0.f;   // pool_dir slots
    float m0 = 0.f, m1 = 0.f, m2 = 0.f, m3 = 0.f;   // sem_dir slots
    __syncthreads();
    const int nwaves = gridDim.x * 4;
    for (int d = blockIdx.x * 4 + w; d < NDST_TOTAL; d += nwaves) {
        int type, ld;
        const float *ssrc, *sdst, *hsrc;
        int ss, soff, ds, doff;
        if (d < 50000)       { type = 0; ld = d;          ssrc = s_ing; ss = 12; soff = 0;  sdst = s_dir; ds = 28; doff = 0;  hsrc = h_ing; }
        else if (d < 100000) { type = 1; ld = d - 50000;  ssrc = s_ing; ss = 12; soff = 4;  sdst = s_dir; ds = 28; doff = 4;  hsrc = h_ing; }
        else if (d < 200000) { type = 2; ld = d - 100000; ssrc = s_dir; ss = 28; soff = 8;  sdst = s_ing; ds = 12; doff = 8;  hsrc = h_dir; }
        else if (d < 250000) { type = 3; ld = d - 200000; ssrc = s_dir; ss = 28; soff = 12; sdst = s_dir; ds = 28; doff = 16; hsrc = h_dir; }
        else                 { type = 4; ld = d - 250000; ssrc = s_dir; ss = 28; soff = 20; sdst = s_dir; ds = 28; doff = 24; hsrc = h_dir; }
        float adst = sdst[(size_t)ld * ds + doff + h];
        int jb = start[d], je = jb + cnt[d];
        float accf = 0.f, dsum = 0.f;
        int j = jb;
        for (; j + 4 <= je; j += 4) {
            int s0 = perm[j], s1 = perm[j + 1], s2 = perm[j + 2], s3 = perm[j + 3];
            float c0 = ssrc[(size_t)s0 * ss + soff + h];
            float c1 = ssrc[(size_t)s1 * ss + soff + h];
            float c2 = ssrc[(size_t)s2 * ss + soff + h];
            float c3 = ssrc[(size_t)s3 * ss + soff + h];
            float g0 = hsrc[(size_t)s0 * 64 + t];
            float g1 = hsrc[(size_t)s1 * 64 + t];
            float g2 = hsrc[(size_t)s2 * 64 + t];
            float g3 = hsrc[(size_t)s3 * 64 + t];
            float a0 = c0 + adst; a0 = a0 > 0.f ? a0 : 0.2f * a0;
            float a1 = c1 + adst; a1 = a1 > 0.f ? a1 : 0.2f * a1;
            float a2 = c2 + adst; a2 = a2 > 0.f ? a2 : 0.2f * a2;
            float a3 = c3 + adst; a3 = a3 > 0.f ? a3 : 0.2f * a3;
            float e0 = __expf(a0), e1 = __expf(a1), e2 = __expf(a2), e3 = __expf(a3);
            dsum += (e0 + e1) + (e2 + e3);
            accf += g0 * e0 + g1 * e1 + g2 * e2 + g3 * e3;
        }
        for (; j < je; ++j) {
            int src = perm[j];
            float a = ssrc[(size_t)src * ss + soff + h] + adst;
            a = a > 0.f ? a : 0.2f * a;
            float ex = __expf(a);
            dsum += ex;
            accf += hsrc[(size_t)src * 64 + t] * ex;
        }
        float v = fmaxf(accf / (dsum + 1e-16f), 0.f);
        if (type == 2) {
            p_ing += v;
        } else {
            srow[w][t] = v;                      // wave-local, no sync needed
            float a2 = bkf;
#pragma unroll
            for (int k = 0; k < 64; ++k) a2 += srow[w][k] * sWk[k * 64 + t];
            float tv = tanhf(a2);
            if (type == 0)      { p0 += v; m0 += tv; }
            else if (type == 1) { p1 += v; m1 += tv; }
            else if (type == 3) { p2 += v; m2 += tv; }
            else                { p3 += v; m3 += tv; }
        }
    }
    float vals[9] = { p_ing, p0, p1, p2, p3, m0, m1, m2, m3 };
    float* outs[9] = { pool_ing, pool_dir, pool_dir + 64, pool_dir + 128,
                       pool_dir + 192, sem_dir, sem_dir + 64, sem_dir + 128,
                       sem_dir + 192 };
    for (int i = 0; i < 9; ++i) {
        __syncthreads();
        sred[w][t] = vals[i];
        __syncthreads();
        if (w == 0)
            atomicAdd(&outs[i][t], sred[0][t] + sred[1][t] + sred[2][t] + sred[3][t]);
    }
}

// ---------------- final: semantic softmax + pools + VAE head ----------------
__global__ __launch_bounds__(64) void final_kernel(
    const float* __restrict__ pool_ing, const float* __restrict__ pool_dir,
    const float* __restrict__ sem_dir, const float* __restrict__ q,
    const float* __restrict__ cond, const float* __restrict__ eps,
    const float* __restrict__ W_mu, const float* __restrict__ b_mu,
    const float* __restrict__ W_lv, const float* __restrict__ b_lv,
    const float* __restrict__ W_fc3, const float* __restrict__ b_fc3,
    const float* __restrict__ W_fc2, const float* __restrict__ b_fc2,
    float* __restrict__ out)
{
    __shared__ float gr[136];
    __shared__ float sc[4], attn[4];
    __shared__ float z[32], hfc[64];
    int t = threadIdx.x;  // 64 threads
    if (t < 4) {
        float s = 0.f;
        for (int f = 0; f < 64; ++f)
            s += (sem_dir[t * 64 + f] / (float)N_DIR) * q[f];
        sc[t] = s;
    }
    gr[t] = pool_ing[t] / (float)N_ING;   // out_ing == o_cont (T=1 softmax)
    __syncthreads();
    if (t == 0) {
        float m = fmaxf(fmaxf(sc[0], sc[1]), fmaxf(sc[2], sc[3]));
        float ssum = 0.f;
        for (int i = 0; i < 4; ++i) { attn[i] = expf(sc[i] - m); ssum += attn[i]; }
        for (int i = 0; i < 4; ++i) attn[i] /= ssum;
    }
    __syncthreads();
    {
        float v = 0.f;
        for (int tt = 0; tt < 4; ++tt)
            v += attn[tt] * (pool_dir[tt * 64 + t] / (float)N_DIR);
        gr[64 + t] = v;
    }
    if (t < 8) gr[128 + t] = cond[t];
    __syncthreads();
    if (t < 32) {
        float m = b_mu[t], lv = b_lv[t];
        for (int i = 0; i < 136; ++i) {
            float g = gr[i];
            m  += g * W_mu[i * 32 + t];
            lv += g * W_lv[i * 32 + t];
        }
        out[16 + t] = m;
        out[48 + t] = lv;
        z[t] = m + eps[t] * expf(0.5f * lv);
    }
    __syncthreads();
    {
        float v = b_fc3[t];
        for (int j = 0; j < 32; ++j) v += z[j] * W_fc3[j * 64 + t];
        hfc[t] = fmaxf(v, 0.f);
    }
    __syncthreads();
    if (t < 16) {
        float v = b_fc2[t];
        for (int f = 0; f < 64; ++f) v += hfc[f] * W_fc2[f * 16 + t];
        out[t] = tanhf(v);
    }
}

extern "C" void kernel_launch(void* const* d_in, const int* in_sizes, int n_in,
                              void* d_out, int out_size, void* d_ws, size_t ws_size,
                              hipStream_t stream) {
    const float* x_ing = (const float*)d_in[0];
    const float* x_dir = (const float*)d_in[1];
    const float* cond  = (const float*)d_in[2];
    const float* eps   = (const float*)d_in[3];
    const int* ei_cooc     = (const int*)d_in[4];
    const int* ei_used     = (const int*)d_in[5];
    const int* ei_contains = (const int*)d_in[6];
    const int* ei_pairs    = (const int*)d_in[7];
    const int* ei_follows  = (const int*)d_in[8];
    const float* W_pi = (const float*)d_in[9];
    const float* b_pi = (const float*)d_in[10];
    const float* W_pd = (const float*)d_in[11];
    const float* b_pd = (const float*)d_in[12];
    const float* Wk   = (const float*)d_in[13];
    const float* bk   = (const float*)d_in[14];
    const float* q    = (const float*)d_in[15];
    const float* W_mu = (const float*)d_in[16];
    const float* b_mu = (const float*)d_in[17];
    const float* W_lv = (const float*)d_in[18];
    const float* b_lv = (const float*)d_in[19];
    const float* W_fc3 = (const float*)d_in[20];
    const float* b_fc3 = (const float*)d_in[21];
    const float* W_fc2 = (const float*)d_in[22];
    const float* b_fc2 = (const float*)d_in[23];
    const float* as_cooc     = (const float*)d_in[24];
    const float* ad_cooc     = (const float*)d_in[25];
    const float* as_used     = (const float*)d_in[26];
    const float* ad_used     = (const float*)d_in[27];
    const float* as_contains = (const float*)d_in[28];
    const float* ad_contains = (const float*)d_in[29];
    const float* as_pairs    = (const float*)d_in[30];
    const float* ad_pairs    = (const float*)d_in[31];
    const float* as_follows  = (const float*)d_in[32];
    const float* ad_follows  = (const float*)d_in[33];

    // ---- workspace layout ----
    float* ws = (float*)d_ws;
    float* h_ing = ws;                          // 6.4M floats
    float* h_dir = h_ing + (size_t)N_ING * 64;  // 3.2M
    float* s_ing = h_dir + (size_t)N_DIR * 64;  // 1.2M   [N_ING][3][4]
    float* s_dir = s_ing + (size_t)N_ING * 12;  // 1.4M   [N_DIR][7][4]
    int*   perm  = (int*)(s_dir + (size_t)N_DIR * 28);  // 5M ints
    int*   rank  = perm + (size_t)5 * NE;       // 5M ints
    int*   start = rank + (size_t)5 * NE;       // 300K
    int*   cnt   = start + NDST_TOTAL;          // 300K  (zeroed region begins here)
    int*   cursor = cnt + NDST_TOTAL;           // 1
    float* pool_ing = (float*)(cursor + 1);     // 64
    float* pool_dir = pool_ing + 64;            // 4*64
    float* sem_dir  = pool_dir + 256;           // 4*64

    // single memset: cnt + cursor + pools (contiguous)
    hipMemsetAsync(cnt, 0, (size_t)(NDST_TOTAL + 1 + 64 + 256 + 256) * sizeof(int), stream);

    // projections + per-node attention scores
    proj_kernel<<<(N_ING * 64) / 256, 256, 0, stream>>>(x_ing, W_pi, b_pi, h_ing, N_ING, 16);
    proj_kernel<<<(N_DIR * 64) / 256, 256, 0, stream>>>(x_dir, W_pd, b_pd, h_dir, N_DIR, 8);
    // ing slots: 0 = src(cooc), 1 = src(used), 2 = dst(contains)
    score_ing_kernel<<<(N_ING * 4 + 255) / 256, 256, 0, stream>>>(
        h_ing, s_ing, N_ING, as_cooc, as_used, ad_contains);
    // dir slots: 0 = dst(cooc), 1 = dst(used), 2 = src(contains),
    //            3 = src(pairs), 4 = dst(pairs), 5 = src(follows), 6 = dst(follows)
    score_dir_kernel<<<(N_DIR * 4 + 255) / 256, 256, 0, stream>>>(
        h_dir, s_dir, N_DIR, ad_cooc, ad_used, as_contains, as_pairs, ad_pairs,
        as_follows, ad_follows);

    // counting-sort CSR build (3 passes, scatter pass atomic-free)
    histrank5_kernel<<<5 * BPT8, 256, 0, stream>>>(
        ei_cooc, ei_used, ei_contains, ei_pairs, ei_follows, cnt, rank);
    offsets_kernel<<<(NDST_TOTAL + 255) / 256, 256, 0, stream>>>(
        cnt, start, NDST_TOTAL, cursor);
    scatterrank5_kernel<<<5 * BPT8, 256, 0, stream>>>(
        ei_cooc, ei_used, ei_contains, ei_pairs, ei_follows, start, rank, perm);

    // single fused aggregation over all 300K dst segments
    agg_all_kernel<<<2048, 256, 0, stream>>>(
        perm, start, cnt, h_ing, h_dir, s_ing, s_dir, Wk, bk,
        pool_ing, pool_dir, sem_dir);

    final_kernel<<<1, 64, 0, stream>>>(
        pool_ing, pool_dir, sem_dir, q, cond, eps,
        W_mu, b_mu, W_lv, b_lv, W_fc3, b_fc3, W_fc2, b_fc2, (float*)d_out);
}

// Round 5
// 799.199 us; speedup vs baseline: 3.3445x; 1.0078x over previous
//
#include <hip/hip_runtime.h>
#include <math.h>

#define N_ING 100000
#define N_DIR 50000
#define NE    1000000
#define NDST_TOTAL 300000   // 50K(cooc)+50K(used)+100K(contains)+50K(pairs)+50K(follows)

// ---------------- projection: h = x @ W + b ----------------
__global__ __launch_bounds__(256) void proj_kernel(
    const float* __restrict__ x, const float* __restrict__ W,
    const float* __restrict__ b, float* __restrict__ h, int N, int F)
{
    __shared__ float sW[16 * 64];
    __shared__ float sb[64];
    for (int i = threadIdx.x; i < F * 64; i += blockDim.x) sW[i] = W[i];
    if (threadIdx.x < 64) sb[threadIdx.x] = b[threadIdx.x];
    __syncthreads();
    int idx = blockIdx.x * blockDim.x + threadIdx.x;
    if (idx >= N * 64) return;
    int n = idx >> 6, f = idx & 63;
    const float* xr = x + (size_t)n * F;
    float s = sb[f];
    for (int i = 0; i < F; ++i) s += xr[i] * sW[i * 64 + f];
    h[idx] = s;
}

// ---------------- attention score precompute ----------------
__global__ __launch_bounds__(256) void score_ing_kernel(
    const float* __restrict__ h, float* __restrict__ s, int N,
    const float* __restrict__ a0, const float* __restrict__ a1,
    const float* __restrict__ a2)
{
    int idx = blockIdx.x * blockDim.x + threadIdx.x;  // n*4 + head
    if (idx >= N * 4) return;
    int n = idx >> 2, hh = idx & 3;
    const float* row = h + (size_t)n * 64 + hh * 16;
    float d0 = 0.f, d1 = 0.f, d2 = 0.f;
    for (int d = 0; d < 16; ++d) {
        float v = row[d];
        d0 += v * a0[hh * 16 + d];
        d1 += v * a1[hh * 16 + d];
        d2 += v * a2[hh * 16 + d];
    }
    float* sr = s + (size_t)n * 12;
    sr[0 + hh] = d0;
    sr[4 + hh] = d1;
    sr[8 + hh] = d2;
}

__global__ __launch_bounds__(256) void score_dir_kernel(
    const float* __restrict__ h, float* __restrict__ s, int N,
    const float* __restrict__ a0, const float* __restrict__ a1,
    const float* __restrict__ a2, const float* __restrict__ a3,
    const float* __restrict__ a4, const float* __restrict__ a5,
    const float* __restrict__ a6)
{
    int idx = blockIdx.x * blockDim.x + threadIdx.x;
    if (idx >= N * 4) return;
    int n = idx >> 2, hh = idx & 3;
    const float* row = h + (size_t)n * 64 + hh * 16;
    float d0 = 0.f, d1 = 0.f, d2 = 0.f, d3 = 0.f, d4 = 0.f, d5 = 0.f, d6 = 0.f;
    for (int d = 0; d < 16; ++d) {
        float v = row[d];
        d0 += v * a0[hh * 16 + d];
        d1 += v * a1[hh * 16 + d];
        d2 += v * a2[hh * 16 + d];
        d3 += v * a3[hh * 16 + d];
        d4 += v * a4[hh * 16 + d];
        d5 += v * a5[hh * 16 + d];
        d6 += v * a6[hh * 16 + d];
    }
    float* sr = s + (size_t)n * 28;
    sr[0  + hh] = d0;
    sr[4  + hh] = d1;
    sr[8  + hh] = d2;
    sr[12 + hh] = d3;
    sr[16 + hh] = d4;
    sr[20 + hh] = d5;
    sr[24 + hh] = d6;
}

// ---------------- CSR pass 1: histogram + per-edge rank, 16 edges/thread ---
// atomic return feeds only a coalesced store (non-blocking); NE % 16 == 0
#define BPT16 245   // 245*256*16 >= 1M
__global__ __launch_bounds__(256) void histrank5_kernel(
    const int* __restrict__ e0, const int* __restrict__ e1,
    const int* __restrict__ e2, const int* __restrict__ e3,
    const int* __restrict__ e4, int* __restrict__ cnt, int* __restrict__ rank)
{
    const int type = blockIdx.x / BPT16;
    const int* ei = type == 0 ? e0 : type == 1 ? e1 : type == 2 ? e2
                  : type == 3 ? e3 : e4;
    const int b = type == 0 ? 0 : type == 1 ? 50000 : type == 2 ? 100000
                : type == 3 ? 200000 : 250000;
    int e = ((blockIdx.x % BPT16) * 256 + threadIdx.x) * 16;
    if (e >= NE) return;
    int4 d0 = *(const int4*)&ei[NE + e];
    int4 d1 = *(const int4*)&ei[NE + e + 4];
    int4 d2 = *(const int4*)&ei[NE + e + 8];
    int4 d3 = *(const int4*)&ei[NE + e + 12];
    int r0  = atomicAdd(&cnt[b + d0.x], 1);
    int r1  = atomicAdd(&cnt[b + d0.y], 1);
    int r2  = atomicAdd(&cnt[b + d0.z], 1);
    int r3  = atomicAdd(&cnt[b + d0.w], 1);
    int r4  = atomicAdd(&cnt[b + d1.x], 1);
    int r5  = atomicAdd(&cnt[b + d1.y], 1);
    int r6  = atomicAdd(&cnt[b + d1.z], 1);
    int r7  = atomicAdd(&cnt[b + d1.w], 1);
    int r8  = atomicAdd(&cnt[b + d2.x], 1);
    int r9  = atomicAdd(&cnt[b + d2.y], 1);
    int r10 = atomicAdd(&cnt[b + d2.z], 1);
    int r11 = atomicAdd(&cnt[b + d2.w], 1);
    int r12 = atomicAdd(&cnt[b + d3.x], 1);
    int r13 = atomicAdd(&cnt[b + d3.y], 1);
    int r14 = atomicAdd(&cnt[b + d3.z], 1);
    int r15 = atomicAdd(&cnt[b + d3.w], 1);
    int* rp = &rank[(size_t)type * NE + e];
    *(int4*)rp        = make_int4(r0,  r1,  r2,  r3);
    *(int4*)(rp + 4)  = make_int4(r4,  r5,  r6,  r7);
    *(int4*)(rp + 8)  = make_int4(r8,  r9,  r10, r11);
    *(int4*)(rp + 12) = make_int4(r12, r13, r14, r15);
}

// ---------------- CSR pass 2: segment offsets (order-free reservation) -----
__global__ __launch_bounds__(256) void offsets_kernel(
    const int* __restrict__ cnt, int* __restrict__ start,
    int n, int* __restrict__ cursor)
{
    __shared__ int sh[256];
    __shared__ int base;
    int i = blockIdx.x * 256 + threadIdx.x;
    int c = (i < n) ? cnt[i] : 0;
    sh[threadIdx.x] = c;
    __syncthreads();
    for (int off = 1; off < 256; off <<= 1) {
        int v = (threadIdx.x >= off) ? sh[threadIdx.x - off] : 0;
        __syncthreads();
        sh[threadIdx.x] += v;
        __syncthreads();
    }
    if (threadIdx.x == 255) base = atomicAdd(cursor, sh[255]);
    __syncthreads();
    if (i < n) start[i] = base + sh[threadIdx.x] - c;  // exclusive
}

// ---------------- CSR pass 3: atomic-free scatter, 16 edges/thread ---------
__global__ __launch_bounds__(256) void scatterrank5_kernel(
    const int* __restrict__ e0, const int* __restrict__ e1,
    const int* __restrict__ e2, const int* __restrict__ e3,
    const int* __restrict__ e4, const int* __restrict__ start,
    const int* __restrict__ rank, int* __restrict__ perm)
{
    const int type = blockIdx.x / BPT16;
    const int* ei = type == 0 ? e0 : type == 1 ? e1 : type == 2 ? e2
                  : type == 3 ? e3 : e4;
    const int b = type == 0 ? 0 : type == 1 ? 50000 : type == 2 ? 100000
                : type == 3 ? 200000 : 250000;
    int e = ((blockIdx.x % BPT16) * 256 + threadIdx.x) * 16;
    if (e >= NE) return;
    const int* rp = &rank[(size_t)type * NE + e];
#pragma unroll
    for (int u = 0; u < 4; ++u) {
        int4 s = *(const int4*)&ei[e + u * 4];
        int4 d = *(const int4*)&ei[NE + e + u * 4];
        int4 r = *(const int4*)(rp + u * 4);
        int p0 = start[b + d.x] + r.x;
        int p1 = start[b + d.y] + r.y;
        int p2 = start[b + d.z] + r.z;
        int p3 = start[b + d.w] + r.w;
        perm[p0] = s.x;
        perm[p1] = s.y;
        perm[p2] = s.z;
        perm[p3] = s.w;
    }
}

// ---------------- fused aggregation, ALL types, 4 edges per instruction ----
// one wave per dst segment; 16 lanes x float4 per edge; zero float atomics
__global__ __launch_bounds__(256) void agg_all_kernel(
    const int* __restrict__ perm, const int* __restrict__ start,
    const int* __restrict__ cnt,
    const float* __restrict__ h_ing, const float* __restrict__ h_dir,
    const float* __restrict__ s_ing, const float* __restrict__ s_dir,
    const float* __restrict__ Wk, const float* __restrict__ bk,
    float* __restrict__ pool_ing, float* __restrict__ pool_dir,
    float* __restrict__ sem_dir)
{
    __shared__ float sWk[64 * 64];
    __shared__ float srow[4][64];
    __shared__ float sred[4][64];
    const int t = threadIdx.x & 63, w = threadIdx.x >> 6;
    const int g  = t >> 4;       // edge group 0..3 (my edge within a 4-pack)
    const int l4 = t & 15;       // my feature quad: features 4*l4 .. 4*l4+3
    const int hq = l4 >> 2;      // head of my features
    for (int i = threadIdx.x; i < 4096; i += 256) sWk[i] = Wk[i];
    const float bkf = bk[t];
    float p_ing = 0.f;
    float p0 = 0.f, p1 = 0.f, p2 = 0.f, p3 = 0.f;   // pool_dir slots
    float m0 = 0.f, m1 = 0.f, m2 = 0.f, m3 = 0.f;   // sem_dir slots
    __syncthreads();
    const int nwaves = gridDim.x * 4;
    for (int d = blockIdx.x * 4 + w; d < NDST_TOTAL; d += nwaves) {
        int type, ld;
        const float *ssrc, *sdst, *hsrc;
        int ss, soff, ds, doff;
        if (d < 50000)       { type = 0; ld = d;          ssrc = s_ing; ss = 12; soff = 0;  sdst = s_dir; ds = 28; doff = 0;  hsrc = h_ing; }
        else if (d < 100000) { type = 1; ld = d - 50000;  ssrc = s_ing; ss = 12; soff = 4;  sdst = s_dir; ds = 28; doff = 4;  hsrc = h_ing; }
        else if (d < 200000) { type = 2; ld = d - 100000; ssrc = s_dir; ss = 28; soff = 8;  sdst = s_ing; ds = 12; doff = 8;  hsrc = h_dir; }
        else if (d < 250000) { type = 3; ld = d - 200000; ssrc = s_dir; ss = 28; soff = 12; sdst = s_dir; ds = 28; doff = 16; hsrc = h_dir; }
        else                 { type = 4; ld = d - 250000; ssrc = s_dir; ss = 28; soff = 20; sdst = s_dir; ds = 28; doff = 24; hsrc = h_dir; }
        float adst = sdst[(size_t)ld * ds + doff + hq];
        int jb = start[d], je = jb + cnt[d];
        float4 acc = make_float4(0.f, 0.f, 0.f, 0.f);
        float dsum = 0.f;
        for (int j = jb; j < je; j += 4) {
            int jj = j + g;
            bool valid = jj < je;
            int src = perm[valid ? jj : je - 1];      // 4 distinct addrs/wave
            float c = ssrc[(size_t)src * ss + soff + hq];
            float4 hv = *(const float4*)&hsrc[(size_t)src * 64 + l4 * 4];
            float a = c + adst;
            a = a > 0.f ? a : 0.2f * a;               // leaky_relu(0.2)
            float e = valid ? __expf(a) : 0.f;        // no shift: |a| O(1)
            dsum += e;
            acc.x += hv.x * e;
            acc.y += hv.y * e;
            acc.z += hv.z * e;
            acc.w += hv.w * e;
        }
        // butterfly-reduce the 4 edge groups (lanes ^16, ^32)
#pragma unroll
        for (int mask = 16; mask <= 32; mask <<= 1) {
            acc.x += __shfl_xor(acc.x, mask, 64);
            acc.y += __shfl_xor(acc.y, mask, 64);
            acc.z += __shfl_xor(acc.z, mask, 64);
            acc.w += __shfl_xor(acc.w, mask, 64);
            dsum  += __shfl_xor(dsum,  mask, 64);
        }
        float inv = 1.f / (dsum + 1e-16f);
        float4 v4 = make_float4(fmaxf(acc.x * inv, 0.f), fmaxf(acc.y * inv, 0.f),
                                fmaxf(acc.z * inv, 0.f), fmaxf(acc.w * inv, 0.f));
        if (g == 0) *(float4*)&srow[w][l4 * 4] = v4;  // rebroadcast layout
        float v = srow[w][t];                          // wave-coherent LDS
        if (type == 2) {
            p_ing += v;
        } else {
            float a2 = bkf;
#pragma unroll
            for (int k = 0; k < 64; ++k) a2 += srow[w][k] * sWk[k * 64 + t];
            float tv = tanhf(a2);
            if (type == 0)      { p0 += v; m0 += tv; }
            else if (type == 1) { p1 += v; m1 += tv; }
            else if (type == 3) { p2 += v; m2 += tv; }
            else                { p3 += v; m3 += tv; }
        }
    }
    float vals[9] = { p_ing, p0, p1, p2, p3, m0, m1, m2, m3 };
    float* outs[9] = { pool_ing, pool_dir, pool_dir + 64, pool_dir + 128,
                       pool_dir + 192, sem_dir, sem_dir + 64, sem_dir + 128,
                       sem_dir + 192 };
    for (int i = 0; i < 9; ++i) {
        __syncthreads();
        sred[w][t] = vals[i];
        __syncthreads();
        if (w == 0)
            atomicAdd(&outs[i][t], sred[0][t] + sred[1][t] + sred[2][t] + sred[3][t]);
    }
}

// ---------------- final: semantic softmax + pools + VAE head ----------------
__global__ __launch_bounds__(64) void final_kernel(
    const float* __restrict__ pool_ing, const float* __restrict__ pool_dir,
    const float* __restrict__ sem_dir, const float* __restrict__ q,
    const float* __restrict__ cond, const float* __restrict__ eps,
    const float* __restrict__ W_mu, const float* __restrict__ b_mu,
    const float* __restrict__ W_lv, const float* __restrict__ b_lv,
    const float* __restrict__ W_fc3, const float* __restrict__ b_fc3,
    const float* __restrict__ W_fc2, const float* __restrict__ b_fc2,
    float* __restrict__ out)
{
    __shared__ float gr[136];
    __shared__ float sc[4], attn[4];
    __shared__ float z[32], hfc[64];
    int t = threadIdx.x;  // 64 threads
    if (t < 4) {
        float s = 0.f;
        for (int f = 0; f < 64; ++f)
            s += (sem_dir[t * 64 + f] / (float)N_DIR) * q[f];
        sc[t] = s;
    }
    gr[t] = pool_ing[t] / (float)N_ING;   // out_ing == o_cont (T=1 softmax)
    __syncthreads();
    if (t == 0) {
        float m = fmaxf(fmaxf(sc[0], sc[1]), fmaxf(sc[2], sc[3]));
        float ssum = 0.f;
        for (int i = 0; i < 4; ++i) { attn[i] = expf(sc[i] - m); ssum += attn[i]; }
        for (int i = 0; i < 4; ++i) attn[i] /= ssum;
    }
    __syncthreads();
    {
        float v = 0.f;
        for (int tt = 0; tt < 4; ++tt)
            v += attn[tt] * (pool_dir[tt * 64 + t] / (float)N_DIR);
        gr[64 + t] = v;
    }
    if (t < 8) gr[128 + t] = cond[t];
    __syncthreads();
    if (t < 32) {
        float m = b_mu[t], lv = b_lv[t];
        for (int i = 0; i < 136; ++i) {
            float g = gr[i];
            m  += g * W_mu[i * 32 + t];
            lv += g * W_lv[i * 32 + t];
        }
        out[16 + t] = m;
        out[48 + t] = lv;
        z[t] = m + eps[t] * expf(0.5f * lv);
    }
    __syncthreads();
    {
        float v = b_fc3[t];
        for (int j = 0; j < 32; ++j) v += z[j] * W_fc3[j * 64 + t];
        hfc[t] = fmaxf(v, 0.f);
    }
    __syncthreads();
    if (t < 16) {
        float v = b_fc2[t];
        for (int f = 0; f < 64; ++f) v += hfc[f] * W_fc2[f * 16 + t];
        out[t] = tanhf(v);
    }
}

extern "C" void kernel_launch(void* const* d_in, const int* in_sizes, int n_in,
                              void* d_out, int out_size, void* d_ws, size_t ws_size,
                              hipStream_t stream) {
    const float* x_ing = (const float*)d_in[0];
    const float* x_dir = (const float*)d_in[1];
    const float* cond  = (const float*)d_in[2];
    const float* eps   = (const float*)d_in[3];
    const int* ei_cooc     = (const int*)d_in[4];
    const int* ei_used     = (const int*)d_in[5];
    const int* ei_contains = (const int*)d_in[6];
    const int* ei_pairs    = (const int*)d_in[7];
    const int* ei_follows  = (const int*)d_in[8];
    const float* W_pi = (const float*)d_in[9];
    const float* b_pi = (const float*)d_in[10];
    const float* W_pd = (const float*)d_in[11];
    const float* b_pd = (const float*)d_in[12];
    const float* Wk   = (const float*)d_in[13];
    const float* bk   = (const float*)d_in[14];
    const float* q    = (const float*)d_in[15];
    const float* W_mu = (const float*)d_in[16];
    const float* b_mu = (const float*)d_in[17];
    const float* W_lv = (const float*)d_in[18];
    const float* b_lv = (const float*)d_in[19];
    const float* W_fc3 = (const float*)d_in[20];
    const float* b_fc3 = (const float*)d_in[21];
    const float* W_fc2 = (const float*)d_in[22];
    const float* b_fc2 = (const float*)d_in[23];
    const float* as_cooc     = (const float*)d_in[24];
    const float* ad_cooc     = (const float*)d_in[25];
    const float* as_used     = (const float*)d_in[26];
    const float* ad_used     = (const float*)d_in[27];
    const float* as_contains = (const float*)d_in[28];
    const float* ad_contains = (const float*)d_in[29];
    const float* as_pairs    = (const float*)d_in[30];
    const float* ad_pairs    = (const float*)d_in[31];
    const float* as_follows  = (const float*)d_in[32];
    const float* ad_follows  = (const float*)d_in[33];

    // ---- workspace layout ----
    float* ws = (float*)d_ws;
    float* h_ing = ws;                          // 6.4M floats
    float* h_dir = h_ing + (size_t)N_ING * 64;  // 3.2M
    float* s_ing = h_dir + (size_t)N_DIR * 64;  // 1.2M   [N_ING][3][4]
    float* s_dir = s_ing + (size_t)N_ING * 12;  // 1.4M   [N_DIR][7][4]
    int*   perm  = (int*)(s_dir + (size_t)N_DIR * 28);  // 5M ints
    int*   rank  = perm + (size_t)5 * NE;       // 5M ints
    int*   start = rank + (size_t)5 * NE;       // 300K
    int*   cnt   = start + NDST_TOTAL;          // 300K  (zeroed region begins here)
    int*   cursor = cnt + NDST_TOTAL;           // 1
    float* pool_ing = (float*)(cursor + 1);     // 64
    float* pool_dir = pool_ing + 64;            // 4*64
    float* sem_dir  = pool_dir + 256;           // 4*64

    // single memset: cnt + cursor + pools (contiguous)
    hipMemsetAsync(cnt, 0, (size_t)(NDST_TOTAL + 1 + 64 + 256 + 256) * sizeof(int), stream);

    // projections + per-node attention scores
    proj_kernel<<<(N_ING * 64) / 256, 256, 0, stream>>>(x_ing, W_pi, b_pi, h_ing, N_ING, 16);
    proj_kernel<<<(N_DIR * 64) / 256, 256, 0, stream>>>(x_dir, W_pd, b_pd, h_dir, N_DIR, 8);
    // ing slots: 0 = src(cooc), 1 = src(used), 2 = dst(contains)
    score_ing_kernel<<<(N_ING * 4 + 255) / 256, 256, 0, stream>>>(
        h_ing, s_ing, N_ING, as_cooc, as_used, ad_contains);
    // dir slots: 0 = dst(cooc), 1 = dst(used), 2 = src(contains),
    //            3 = src(pairs), 4 = dst(pairs), 5 = src(follows), 6 = dst(follows)
    score_dir_kernel<<<(N_DIR * 4 + 255) / 256, 256, 0, stream>>>(
        h_dir, s_dir, N_DIR, ad_cooc, ad_used, as_contains, as_pairs, ad_pairs,
        as_follows, ad_follows);

    // counting-sort CSR build (3 passes, scatter pass atomic-free)
    histrank5_kernel<<<5 * BPT16, 256, 0, stream>>>(
        ei_cooc, ei_used, ei_contains, ei_pairs, ei_follows, cnt, rank);
    offsets_kernel<<<(NDST_TOTAL + 255) / 256, 256, 0, stream>>>(
        cnt, start, NDST_TOTAL, cursor);
    scatterrank5_kernel<<<5 * BPT16, 256, 0, stream>>>(
        ei_cooc, ei_used, ei_contains, ei_pairs, ei_follows, start, rank, perm);

    // single fused aggregation over all 300K dst segments
    agg_all_kernel<<<2048, 256, 0, stream>>>(
        perm, start, cnt, h_ing, h_dir, s_ing, s_dir, Wk, bk,
        pool_ing, pool_dir, sem_dir);

    final_kernel<<<1, 64, 0, stream>>>(
        pool_ing, pool_dir, sem_dir, q, cond, eps,
        W_mu, b_mu, W_lv, b_lv, W_fc3, b_fc3, W_fc2, b_fc2, (float*)d_out);
}

// Round 6
// 707.835 us; speedup vs baseline: 3.7761x; 1.1291x over previous
//
#include <hip/hip_runtime.h>
#include <hip/hip_bf16.h>
#include <math.h>

#define N_ING 100000
#define N_DIR 50000
#define NE    1000000
#define NDST_TOTAL 300000   // 50K(cooc)+50K(used)+100K(contains)+50K(pairs)+50K(follows)

__device__ __forceinline__ float b2f(unsigned short u) {
    return __uint_as_float((unsigned)u << 16);
}

// ---------------- projection: h = x @ W + b  (bf16 output rows) ------------
__global__ __launch_bounds__(256) void proj_kernel(
    const float* __restrict__ x, const float* __restrict__ W,
    const float* __restrict__ b, __hip_bfloat16* __restrict__ h, int N, int F)
{
    __shared__ float sW[16 * 64];
    __shared__ float sb[64];
    for (int i = threadIdx.x; i < F * 64; i += blockDim.x) sW[i] = W[i];
    if (threadIdx.x < 64) sb[threadIdx.x] = b[threadIdx.x];
    __syncthreads();
    int idx = blockIdx.x * blockDim.x + threadIdx.x;
    if (idx >= N * 64) return;
    int n = idx >> 6, f = idx & 63;
    const float* xr = x + (size_t)n * F;
    float s = sb[f];
    for (int i = 0; i < F; ++i) s += xr[i] * sW[i * 64 + f];
    h[idx] = __float2bfloat16(s);
}

// ---------------- attention score precompute (reads bf16 h) ----------------
__global__ __launch_bounds__(256) void score_ing_kernel(
    const __hip_bfloat16* __restrict__ h, float* __restrict__ s, int N,
    const float* __restrict__ a0, const float* __restrict__ a1,
    const float* __restrict__ a2)
{
    int idx = blockIdx.x * blockDim.x + threadIdx.x;  // n*4 + head
    if (idx >= N * 4) return;
    int n = idx >> 2, hh = idx & 3;
    const __hip_bfloat16* row = h + (size_t)n * 64 + hh * 16;
    float d0 = 0.f, d1 = 0.f, d2 = 0.f;
    for (int d = 0; d < 16; ++d) {
        float v = __bfloat162float(row[d]);
        d0 += v * a0[hh * 16 + d];
        d1 += v * a1[hh * 16 + d];
        d2 += v * a2[hh * 16 + d];
    }
    float* sr = s + (size_t)n * 12;
    sr[0 + hh] = d0;
    sr[4 + hh] = d1;
    sr[8 + hh] = d2;
}

__global__ __launch_bounds__(256) void score_dir_kernel(
    const __hip_bfloat16* __restrict__ h, float* __restrict__ s, int N,
    const float* __restrict__ a0, const float* __restrict__ a1,
    const float* __restrict__ a2, const float* __restrict__ a3,
    const float* __restrict__ a4, const float* __restrict__ a5,
    const float* __restrict__ a6)
{
    int idx = blockIdx.x * blockDim.x + threadIdx.x;
    if (idx >= N * 4) return;
    int n = idx >> 2, hh = idx & 3;
    const __hip_bfloat16* row = h + (size_t)n * 64 + hh * 16;
    float d0 = 0.f, d1 = 0.f, d2 = 0.f, d3 = 0.f, d4 = 0.f, d5 = 0.f, d6 = 0.f;
    for (int d = 0; d < 16; ++d) {
        float v = __bfloat162float(row[d]);
        d0 += v * a0[hh * 16 + d];
        d1 += v * a1[hh * 16 + d];
        d2 += v * a2[hh * 16 + d];
        d3 += v * a3[hh * 16 + d];
        d4 += v * a4[hh * 16 + d];
        d5 += v * a5[hh * 16 + d];
        d6 += v * a6[hh * 16 + d];
    }
    float* sr = s + (size_t)n * 28;
    sr[0  + hh] = d0;
    sr[4  + hh] = d1;
    sr[8  + hh] = d2;
    sr[12 + hh] = d3;
    sr[16 + hh] = d4;
    sr[20 + hh] = d5;
    sr[24 + hh] = d6;
}

// ---------------- CSR pass 1: histogram + per-edge rank, 16 edges/thread ---
#define BPT16 245   // 245*256*16 >= 1M
__global__ __launch_bounds__(256) void histrank5_kernel(
    const int* __restrict__ e0, const int* __restrict__ e1,
    const int* __restrict__ e2, const int* __restrict__ e3,
    const int* __restrict__ e4, int* __restrict__ cnt, int* __restrict__ rank)
{
    const int type = blockIdx.x / BPT16;
    const int* ei = type == 0 ? e0 : type == 1 ? e1 : type == 2 ? e2
                  : type == 3 ? e3 : e4;
    const int b = type == 0 ? 0 : type == 1 ? 50000 : type == 2 ? 100000
                : type == 3 ? 200000 : 250000;
    int e = ((blockIdx.x % BPT16) * 256 + threadIdx.x) * 16;
    if (e >= NE) return;
    int4 d0 = *(const int4*)&ei[NE + e];
    int4 d1 = *(const int4*)&ei[NE + e + 4];
    int4 d2 = *(const int4*)&ei[NE + e + 8];
    int4 d3 = *(const int4*)&ei[NE + e + 12];
    int r0  = atomicAdd(&cnt[b + d0.x], 1);
    int r1  = atomicAdd(&cnt[b + d0.y], 1);
    int r2  = atomicAdd(&cnt[b + d0.z], 1);
    int r3  = atomicAdd(&cnt[b + d0.w], 1);
    int r4  = atomicAdd(&cnt[b + d1.x], 1);
    int r5  = atomicAdd(&cnt[b + d1.y], 1);
    int r6  = atomicAdd(&cnt[b + d1.z], 1);
    int r7  = atomicAdd(&cnt[b + d1.w], 1);
    int r8  = atomicAdd(&cnt[b + d2.x], 1);
    int r9  = atomicAdd(&cnt[b + d2.y], 1);
    int r10 = atomicAdd(&cnt[b + d2.z], 1);
    int r11 = atomicAdd(&cnt[b + d2.w], 1);
    int r12 = atomicAdd(&cnt[b + d3.x], 1);
    int r13 = atomicAdd(&cnt[b + d3.y], 1);
    int r14 = atomicAdd(&cnt[b + d3.z], 1);
    int r15 = atomicAdd(&cnt[b + d3.w], 1);
    int* rp = &rank[(size_t)type * NE + e];
    *(int4*)rp        = make_int4(r0,  r1,  r2,  r3);
    *(int4*)(rp + 4)  = make_int4(r4,  r5,  r6,  r7);
    *(int4*)(rp + 8)  = make_int4(r8,  r9,  r10, r11);
    *(int4*)(rp + 12) = make_int4(r12, r13, r14, r15);
}

// ---------------- CSR pass 2: segment offsets (order-free reservation) -----
__global__ __launch_bounds__(256) void offsets_kernel(
    const int* __restrict__ cnt, int* __restrict__ start,
    int n, int* __restrict__ cursor)
{
    __shared__ int sh[256];
    __shared__ int base;
    int i = blockIdx.x * 256 + threadIdx.x;
    int c = (i < n) ? cnt[i] : 0;
    sh[threadIdx.x] = c;
    __syncthreads();
    for (int off = 1; off < 256; off <<= 1) {
        int v = (threadIdx.x >= off) ? sh[threadIdx.x - off] : 0;
        __syncthreads();
        sh[threadIdx.x] += v;
        __syncthreads();
    }
    if (threadIdx.x == 255) base = atomicAdd(cursor, sh[255]);
    __syncthreads();
    if (i < n) start[i] = base + sh[threadIdx.x] - c;  // exclusive
}

// ---------------- CSR pass 3: atomic-free scatter, 16 edges/thread ---------
__global__ __launch_bounds__(256) void scatterrank5_kernel(
    const int* __restrict__ e0, const int* __restrict__ e1,
    const int* __restrict__ e2, const int* __restrict__ e3,
    const int* __restrict__ e4, const int* __restrict__ start,
    const int* __restrict__ rank, int* __restrict__ perm)
{
    const int type = blockIdx.x / BPT16;
    const int* ei = type == 0 ? e0 : type == 1 ? e1 : type == 2 ? e2
                  : type == 3 ? e3 : e4;
    const int b = type == 0 ? 0 : type == 1 ? 50000 : type == 2 ? 100000
                : type == 3 ? 200000 : 250000;
    int e = ((blockIdx.x % BPT16) * 256 + threadIdx.x) * 16;
    if (e >= NE) return;
    const int* rp = &rank[(size_t)type * NE + e];
#pragma unroll
    for (int u = 0; u < 4; ++u) {
        int4 s = *(const int4*)&ei[e + u * 4];
        int4 d = *(const int4*)&ei[NE + e + u * 4];
        int4 r = *(const int4*)(rp + u * 4);
        int p0 = start[b + d.x] + r.x;
        int p1 = start[b + d.y] + r.y;
        int p2 = start[b + d.z] + r.z;
        int p3 = start[b + d.w] + r.w;
        perm[p0] = s.x;
        perm[p1] = s.y;
        perm[p2] = s.z;
        perm[p3] = s.w;
    }
}

// ---------------- fused aggregation: bf16 rows, 8 edges per iteration ------
// one wave per dst segment; 16 lanes x 4 bf16 per edge; zero float atomics
__global__ __launch_bounds__(256) void agg_all_kernel(
    const int* __restrict__ perm, const int* __restrict__ start,
    const int* __restrict__ cnt,
    const __hip_bfloat16* __restrict__ h_ing,
    const __hip_bfloat16* __restrict__ h_dir,
    const float* __restrict__ s_ing, const float* __restrict__ s_dir,
    const float* __restrict__ Wk, const float* __restrict__ bk,
    float* __restrict__ pool_ing, float* __restrict__ pool_dir,
    float* __restrict__ sem_dir)
{
    __shared__ float sWk[64 * 64];
    __shared__ float srow[4][64];
    __shared__ float sred[4][64];
    const int t = threadIdx.x & 63, w = threadIdx.x >> 6;
    const int g  = t >> 4;       // edge group 0..3 (my edge within a 4-pack)
    const int l4 = t & 15;       // my feature quad: features 4*l4 .. 4*l4+3
    const int hq = l4 >> 2;      // head of my features
    for (int i = threadIdx.x; i < 4096; i += 256) sWk[i] = Wk[i];
    const float bkf = bk[t];
    float p_ing = 0.f;
    float p0 = 0.f, p1 = 0.f, p2 = 0.f, p3 = 0.f;   // pool_dir slots
    float m0 = 0.f, m1 = 0.f, m2 = 0.f, m3 = 0.f;   // sem_dir slots
    __syncthreads();
    const int nwaves = gridDim.x * 4;
    for (int d = blockIdx.x * 4 + w; d < NDST_TOTAL; d += nwaves) {
        int type, ld;
        const float *ssrc, *sdst;
        const __hip_bfloat16* hsrc;
        int ss, soff, ds, doff;
        if (d < 50000)       { type = 0; ld = d;          ssrc = s_ing; ss = 12; soff = 0;  sdst = s_dir; ds = 28; doff = 0;  hsrc = h_ing; }
        else if (d < 100000) { type = 1; ld = d - 50000;  ssrc = s_ing; ss = 12; soff = 4;  sdst = s_dir; ds = 28; doff = 4;  hsrc = h_ing; }
        else if (d < 200000) { type = 2; ld = d - 100000; ssrc = s_dir; ss = 28; soff = 8;  sdst = s_ing; ds = 12; doff = 8;  hsrc = h_dir; }
        else if (d < 250000) { type = 3; ld = d - 200000; ssrc = s_dir; ss = 28; soff = 12; sdst = s_dir; ds = 28; doff = 16; hsrc = h_dir; }
        else                 { type = 4; ld = d - 250000; ssrc = s_dir; ss = 28; soff = 20; sdst = s_dir; ds = 28; doff = 24; hsrc = h_dir; }
        float adst = sdst[(size_t)ld * ds + doff + hq];
        int jb = start[d], je = jb + cnt[d];
        float4 acc = make_float4(0.f, 0.f, 0.f, 0.f);
        float dsum = 0.f;
        for (int j = jb; j < je; j += 8) {
            int j0 = j + g, j1 = j + 4 + g;
            bool v0 = j0 < je, v1 = j1 < je;
            int s0 = perm[v0 ? j0 : je - 1];
            int s1 = perm[v1 ? j1 : je - 1];
            float c0 = ssrc[(size_t)s0 * ss + soff + hq];
            float c1 = ssrc[(size_t)s1 * ss + soff + hq];
            ushort4 u0 = *(const ushort4*)(hsrc + (size_t)s0 * 64 + l4 * 4);
            ushort4 u1 = *(const ushort4*)(hsrc + (size_t)s1 * 64 + l4 * 4);
            float a0 = c0 + adst; a0 = a0 > 0.f ? a0 : 0.2f * a0;
            float a1 = c1 + adst; a1 = a1 > 0.f ? a1 : 0.2f * a1;
            float e0 = v0 ? __expf(a0) : 0.f;
            float e1 = v1 ? __expf(a1) : 0.f;
            dsum += e0 + e1;
            acc.x += b2f(u0.x) * e0 + b2f(u1.x) * e1;
            acc.y += b2f(u0.y) * e0 + b2f(u1.y) * e1;
            acc.z += b2f(u0.z) * e0 + b2f(u1.z) * e1;
            acc.w += b2f(u0.w) * e0 + b2f(u1.w) * e1;
        }
        // butterfly-reduce the 4 edge groups (lanes ^16, ^32)
#pragma unroll
        for (int mask = 16; mask <= 32; mask <<= 1) {
            acc.x += __shfl_xor(acc.x, mask, 64);
            acc.y += __shfl_xor(acc.y, mask, 64);
            acc.z += __shfl_xor(acc.z, mask, 64);
            acc.w += __shfl_xor(acc.w, mask, 64);
            dsum  += __shfl_xor(dsum,  mask, 64);
        }
        float inv = 1.f / (dsum + 1e-16f);
        float4 v4 = make_float4(fmaxf(acc.x * inv, 0.f), fmaxf(acc.y * inv, 0.f),
                                fmaxf(acc.z * inv, 0.f), fmaxf(acc.w * inv, 0.f));
        if (g == 0) *(float4*)&srow[w][l4 * 4] = v4;  // rebroadcast layout
        float v = srow[w][t];                          // wave-coherent LDS
        if (type == 2) {
            p_ing += v;
        } else {
            float a2 = bkf;
#pragma unroll
            for (int k = 0; k < 64; ++k) a2 += srow[w][k] * sWk[k * 64 + t];
            float tv = tanhf(a2);
            if (type == 0)      { p0 += v; m0 += tv; }
            else if (type == 1) { p1 += v; m1 += tv; }
            else if (type == 3) { p2 += v; m2 += tv; }
            else                { p3 += v; m3 += tv; }
        }
    }
    float vals[9] = { p_ing, p0, p1, p2, p3, m0, m1, m2, m3 };
    float* outs[9] = { pool_ing, pool_dir, pool_dir + 64, pool_dir + 128,
                       pool_dir + 192, sem_dir, sem_dir + 64, sem_dir + 128,
                       sem_dir + 192 };
    for (int i = 0; i < 9; ++i) {
        __syncthreads();
        sred[w][t] = vals[i];
        __syncthreads();
        if (w == 0)
            atomicAdd(&outs[i][t], sred[0][t] + sred[1][t] + sred[2][t] + sred[3][t]);
    }
}

// ---------------- final: semantic softmax + pools + VAE head ----------------
__global__ __launch_bounds__(64) void final_kernel(
    const float* __restrict__ pool_ing, const float* __restrict__ pool_dir,
    const float* __restrict__ sem_dir, const float* __restrict__ q,
    const float* __restrict__ cond, const float* __restrict__ eps,
    const float* __restrict__ W_mu, const float* __restrict__ b_mu,
    const float* __restrict__ W_lv, const float* __restrict__ b_lv,
    const float* __restrict__ W_fc3, const float* __restrict__ b_fc3,
    const float* __restrict__ W_fc2, const float* __restrict__ b_fc2,
    float* __restrict__ out)
{
    __shared__ float gr[136];
    __shared__ float sc[4], attn[4];
    __shared__ float z[32], hfc[64];
    int t = threadIdx.x;  // 64 threads
    if (t < 4) {
        float s = 0.f;
        for (int f = 0; f < 64; ++f)
            s += (sem_dir[t * 64 + f] / (float)N_DIR) * q[f];
        sc[t] = s;
    }
    gr[t] = pool_ing[t] / (float)N_ING;   // out_ing == o_cont (T=1 softmax)
    __syncthreads();
    if (t == 0) {
        float m = fmaxf(fmaxf(sc[0], sc[1]), fmaxf(sc[2], sc[3]));
        float ssum = 0.f;
        for (int i = 0; i < 4; ++i) { attn[i] = expf(sc[i] - m); ssum += attn[i]; }
        for (int i = 0; i < 4; ++i) attn[i] /= ssum;
    }
    __syncthreads();
    {
        float v = 0.f;
        for (int tt = 0; tt < 4; ++tt)
            v += attn[tt] * (pool_dir[tt * 64 + t] / (float)N_DIR);
        gr[64 + t] = v;
    }
    if (t < 8) gr[128 + t] = cond[t];
    __syncthreads();
    if (t < 32) {
        float m = b_mu[t], lv = b_lv[t];
        for (int i = 0; i < 136; ++i) {
            float g = gr[i];
            m  += g * W_mu[i * 32 + t];
            lv += g * W_lv[i * 32 + t];
        }
        out[16 + t] = m;
        out[48 + t] = lv;
        z[t] = m + eps[t] * expf(0.5f * lv);
    }
    __syncthreads();
    {
        float v = b_fc3[t];
        for (int j = 0; j < 32; ++j) v += z[j] * W_fc3[j * 64 + t];
        hfc[t] = fmaxf(v, 0.f);
    }
    __syncthreads();
    if (t < 16) {
        float v = b_fc2[t];
        for (int f = 0; f < 64; ++f) v += hfc[f] * W_fc2[f * 16 + t];
        out[t] = tanhf(v);
    }
}

extern "C" void kernel_launch(void* const* d_in, const int* in_sizes, int n_in,
                              void* d_out, int out_size, void* d_ws, size_t ws_size,
                              hipStream_t stream) {
    const float* x_ing = (const float*)d_in[0];
    const float* x_dir = (const float*)d_in[1];
    const float* cond  = (const float*)d_in[2];
    const float* eps   = (const float*)d_in[3];
    const int* ei_cooc     = (const int*)d_in[4];
    const int* ei_used     = (const int*)d_in[5];
    const int* ei_contains = (const int*)d_in[6];
    const int* ei_pairs    = (const int*)d_in[7];
    const int* ei_follows  = (const int*)d_in[8];
    const float* W_pi = (const float*)d_in[9];
    const float* b_pi = (const float*)d_in[10];
    const float* W_pd = (const float*)d_in[11];
    const float* b_pd = (const float*)d_in[12];
    const float* Wk   = (const float*)d_in[13];
    const float* bk   = (const float*)d_in[14];
    const float* q    = (const float*)d_in[15];
    const float* W_mu = (const float*)d_in[16];
    const float* b_mu = (const float*)d_in[17];
    const float* W_lv = (const float*)d_in[18];
    const float* b_lv = (const float*)d_in[19];
    const float* W_fc3 = (const float*)d_in[20];
    const float* b_fc3 = (const float*)d_in[21];
    const float* W_fc2 = (const float*)d_in[22];
    const float* b_fc2 = (const float*)d_in[23];
    const float* as_cooc     = (const float*)d_in[24];
    const float* ad_cooc     = (const float*)d_in[25];
    const float* as_used     = (const float*)d_in[26];
    const float* ad_used     = (const float*)d_in[27];
    const float* as_contains = (const float*)d_in[28];
    const float* ad_contains = (const float*)d_in[29];
    const float* as_pairs    = (const float*)d_in[30];
    const float* ad_pairs    = (const float*)d_in[31];
    const float* as_follows  = (const float*)d_in[32];
    const float* ad_follows  = (const float*)d_in[33];

    // ---- workspace layout ----
    __hip_bfloat16* h_ing = (__hip_bfloat16*)d_ws;            // 6.4M bf16
    __hip_bfloat16* h_dir = h_ing + (size_t)N_ING * 64;       // 3.2M bf16
    float* s_ing = (float*)(h_dir + (size_t)N_DIR * 64);      // 1.2M fp32 [N_ING][3][4]
    float* s_dir = s_ing + (size_t)N_ING * 12;                // 1.4M fp32 [N_DIR][7][4]
    int*   perm  = (int*)(s_dir + (size_t)N_DIR * 28);        // 5M ints
    int*   rank  = perm + (size_t)5 * NE;                     // 5M ints
    int*   start = rank + (size_t)5 * NE;                     // 300K
    int*   cnt   = start + NDST_TOTAL;                        // 300K (zeroed region begins here)
    int*   cursor = cnt + NDST_TOTAL;                         // 1
    float* pool_ing = (float*)(cursor + 1);                   // 64
    float* pool_dir = pool_ing + 64;                          // 4*64
    float* sem_dir  = pool_dir + 256;                         // 4*64

    // single memset: cnt + cursor + pools (contiguous)
    hipMemsetAsync(cnt, 0, (size_t)(NDST_TOTAL + 1 + 64 + 256 + 256) * sizeof(int), stream);

    // projections + per-node attention scores
    proj_kernel<<<(N_ING * 64) / 256, 256, 0, stream>>>(x_ing, W_pi, b_pi, h_ing, N_ING, 16);
    proj_kernel<<<(N_DIR * 64) / 256, 256, 0, stream>>>(x_dir, W_pd, b_pd, h_dir, N_DIR, 8);
    // ing slots: 0 = src(cooc), 1 = src(used), 2 = dst(contains)
    score_ing_kernel<<<(N_ING * 4 + 255) / 256, 256, 0, stream>>>(
        h_ing, s_ing, N_ING, as_cooc, as_used, ad_contains);
    // dir slots: 0 = dst(cooc), 1 = dst(used), 2 = src(contains),
    //            3 = src(pairs), 4 = dst(pairs), 5 = src(follows), 6 = dst(follows)
    score_dir_kernel<<<(N_DIR * 4 + 255) / 256, 256, 0, stream>>>(
        h_dir, s_dir, N_DIR, ad_cooc, ad_used, as_contains, as_pairs, ad_pairs,
        as_follows, ad_follows);

    // counting-sort CSR build (3 passes, scatter pass atomic-free)
    histrank5_kernel<<<5 * BPT16, 256, 0, stream>>>(
        ei_cooc, ei_used, ei_contains, ei_pairs, ei_follows, cnt, rank);
    offsets_kernel<<<(NDST_TOTAL + 255) / 256, 256, 0, stream>>>(
        cnt, start, NDST_TOTAL, cursor);
    scatterrank5_kernel<<<5 * BPT16, 256, 0, stream>>>(
        ei_cooc, ei_used, ei_contains, ei_pairs, ei_follows, start, rank, perm);

    // single fused aggregation over all 300K dst segments
    agg_all_kernel<<<2048, 256, 0, stream>>>(
        perm, start, cnt, h_ing, h_dir, s_ing, s_dir, Wk, bk,
        pool_ing, pool_dir, sem_dir);

    final_kernel<<<1, 64, 0, stream>>>(
        pool_ing, pool_dir, sem_dir, q, cond, eps,
        W_mu, b_mu, W_lv, b_lv, W_fc3, b_fc3, W_fc2, b_fc2, (float*)d_out);
}

// Round 7
// 685.478 us; speedup vs baseline: 3.8993x; 1.0326x over previous
//
#include <hip/hip_runtime.h>
#include <math.h>

#define N_ING 100000
#define N_DIR 50000
#define NE    1000000
#define NDST_TOTAL 300000   // 50K(cooc)+50K(used)+100K(contains)+50K(pairs)+50K(follows)
#define BPT16 245           // 245*256*16 >= 1M
#define NBH   (5 * BPT16)   // 1225 histrank blocks
#define NB_ING 25000        // 100000/4 nodes per block
#define NB_DIR 12500

typedef float v2f __attribute__((ext_vector_type(2)));

#define WGA(p) __hip_atomic_fetch_add((p), 1, __ATOMIC_RELAXED, __HIP_MEMORY_SCOPE_WORKGROUP)

// ============ K1: histrank (XCD-local atomics) + fused proj+score ==========
__global__ __launch_bounds__(256) void mega_kernel(
    const int* __restrict__ e0, const int* __restrict__ e1,
    const int* __restrict__ e2, const int* __restrict__ e3,
    const int* __restrict__ e4,
    int* __restrict__ cnt8, int* __restrict__ rank,
    const float* __restrict__ x_ing, const float* __restrict__ W_pi,
    const float* __restrict__ b_pi,
    const float* __restrict__ as_cooc, const float* __restrict__ as_used,
    const float* __restrict__ ad_contains,
    unsigned* __restrict__ h8_ing, float* __restrict__ s_ing,
    const float* __restrict__ x_dir, const float* __restrict__ W_pd,
    const float* __restrict__ b_pd,
    const float* __restrict__ ad_cooc, const float* __restrict__ ad_used,
    const float* __restrict__ as_contains, const float* __restrict__ as_pairs,
    const float* __restrict__ ad_pairs, const float* __restrict__ as_follows,
    const float* __restrict__ ad_follows,
    unsigned* __restrict__ h8_dir, float* __restrict__ s_dir)
{
    __shared__ float sW[16 * 64];
    __shared__ float sbb[64];
    __shared__ float satt[7 * 64];
    __shared__ float sx[4][16];
    __shared__ float srow[4][64];

    const int bid = blockIdx.x;
    if (bid < NBH) {
        // ---------- histogram + rank, 16 edges/thread, XCD-private ----------
        unsigned xcc;
        asm volatile("s_getreg_b32 %0, hwreg(HW_REG_XCC_ID)" : "=s"(xcc));
        xcc &= 7;
        const int type = bid / BPT16;
        const int* ei = type == 0 ? e0 : type == 1 ? e1 : type == 2 ? e2
                      : type == 3 ? e3 : e4;
        const int b = type == 0 ? 0 : type == 1 ? 50000 : type == 2 ? 100000
                    : type == 3 ? 200000 : 250000;
        int e = ((bid % BPT16) * 256 + threadIdx.x) * 16;
        if (e >= NE) return;
        int* cb = cnt8 + (size_t)xcc * NDST_TOTAL + b;
        const unsigned xb = xcc << 24;
        int4 d0 = *(const int4*)&ei[NE + e];
        int4 d1 = *(const int4*)&ei[NE + e + 4];
        int4 d2 = *(const int4*)&ei[NE + e + 8];
        int4 d3 = *(const int4*)&ei[NE + e + 12];
        int r0  = WGA(&cb[d0.x]) | xb;
        int r1  = WGA(&cb[d0.y]) | xb;
        int r2  = WGA(&cb[d0.z]) | xb;
        int r3  = WGA(&cb[d0.w]) | xb;
        int r4  = WGA(&cb[d1.x]) | xb;
        int r5  = WGA(&cb[d1.y]) | xb;
        int r6  = WGA(&cb[d1.z]) | xb;
        int r7  = WGA(&cb[d1.w]) | xb;
        int r8  = WGA(&cb[d2.x]) | xb;
        int r9  = WGA(&cb[d2.y]) | xb;
        int r10 = WGA(&cb[d2.z]) | xb;
        int r11 = WGA(&cb[d2.w]) | xb;
        int r12 = WGA(&cb[d3.x]) | xb;
        int r13 = WGA(&cb[d3.y]) | xb;
        int r14 = WGA(&cb[d3.z]) | xb;
        int r15 = WGA(&cb[d3.w]) | xb;
        int* rp = &rank[(size_t)type * NE + e];
        *(int4*)rp        = make_int4(r0,  r1,  r2,  r3);
        *(int4*)(rp + 4)  = make_int4(r4,  r5,  r6,  r7);
        *(int4*)(rp + 8)  = make_int4(r8,  r9,  r10, r11);
        *(int4*)(rp + 12) = make_int4(r12, r13, r14, r15);
    } else if (bid < NBH + NB_ING) {
        // ---------- proj + fp8 pack + scores, ingredient nodes --------------
        const int tid = threadIdx.x, g = tid >> 6, t = tid & 63;
        for (int i = tid; i < 16 * 64; i += 256) sW[i] = W_pi[i];
        if (tid < 64) {
            sbb[tid] = b_pi[tid];
            satt[tid]       = as_cooc[tid];
            satt[64 + tid]  = as_used[tid];
            satt[128 + tid] = ad_contains[tid];
        }
        const int n = (bid - NBH) * 4 + g;
        if (t < 16) sx[g][t] = x_ing[(size_t)n * 16 + t];
        __syncthreads();
        float s = sbb[t];
#pragma unroll
        for (int i = 0; i < 16; ++i) s += sx[g][i] * sW[i * 64 + t];
        srow[g][t] = s;
        __syncthreads();
        if (t < 16) {
            int w0 = __builtin_amdgcn_cvt_pk_fp8_f32(srow[g][t * 4], srow[g][t * 4 + 1], 0, false);
            int w  = __builtin_amdgcn_cvt_pk_fp8_f32(srow[g][t * 4 + 2], srow[g][t * 4 + 3], w0, true);
            h8_ing[(size_t)n * 16 + t] = (unsigned)w;
        }
        if (t < 12) {
            int slot = t >> 2, hh = t & 3;
            float sc = 0.f;
#pragma unroll
            for (int d = 0; d < 16; ++d)
                sc += srow[g][hh * 16 + d] * satt[slot * 64 + hh * 16 + d];
            s_ing[(size_t)n * 12 + t] = sc;
        }
    } else {
        // ---------- proj + fp8 pack + scores, direction nodes ---------------
        const int tid = threadIdx.x, g = tid >> 6, t = tid & 63;
        for (int i = tid; i < 8 * 64; i += 256) sW[i] = W_pd[i];
        if (tid < 64) {
            sbb[tid] = b_pd[tid];
            satt[tid]        = ad_cooc[tid];
            satt[64  + tid]  = ad_used[tid];
            satt[128 + tid]  = as_contains[tid];
            satt[192 + tid]  = as_pairs[tid];
            satt[256 + tid]  = ad_pairs[tid];
            satt[320 + tid]  = as_follows[tid];
            satt[384 + tid]  = ad_follows[tid];
        }
        const int n = (bid - NBH - NB_ING) * 4 + g;
        if (t < 8) sx[g][t] = x_dir[(size_t)n * 8 + t];
        __syncthreads();
        float s = sbb[t];
#pragma unroll
        for (int i = 0; i < 8; ++i) s += sx[g][i] * sW[i * 64 + t];
        srow[g][t] = s;
        __syncthreads();
        if (t < 16) {
            int w0 = __builtin_amdgcn_cvt_pk_fp8_f32(srow[g][t * 4], srow[g][t * 4 + 1], 0, false);
            int w  = __builtin_amdgcn_cvt_pk_fp8_f32(srow[g][t * 4 + 2], srow[g][t * 4 + 3], w0, true);
            h8_dir[(size_t)n * 16 + t] = (unsigned)w;
        }
        if (t < 28) {
            int slot = t >> 2, hh = t & 3;
            float sc = 0.f;
#pragma unroll
            for (int d = 0; d < 16; ++d)
                sc += srow[g][hh * 16 + d] * satt[slot * 64 + hh * 16 + d];
            s_dir[(size_t)n * 28 + t] = sc;
        }
    }
}

// ============ offsets: sum 8 XCD copies, global scan, per-XCD bases ========
__global__ __launch_bounds__(256) void offsets_kernel(
    const int* __restrict__ cnt8, int* __restrict__ start,
    int* __restrict__ cnttot, int* __restrict__ base8, int* __restrict__ cursor)
{
    __shared__ int sh[256];
    __shared__ int bw;
    int i = blockIdx.x * 256 + threadIdx.x;
    int c[8];
    int tot = 0;
    if (i < NDST_TOTAL) {
#pragma unroll
        for (int x = 0; x < 8; ++x) {
            c[x] = cnt8[(size_t)x * NDST_TOTAL + i];
            tot += c[x];
        }
    }
    sh[threadIdx.x] = tot;
    __syncthreads();
    for (int off = 1; off < 256; off <<= 1) {
        int v = (threadIdx.x >= off) ? sh[threadIdx.x - off] : 0;
        __syncthreads();
        sh[threadIdx.x] += v;
        __syncthreads();
    }
    if (threadIdx.x == 255) bw = atomicAdd(cursor, sh[255]);
    __syncthreads();
    if (i < NDST_TOTAL) {
        int st = bw + sh[threadIdx.x] - tot;  // exclusive
        start[i] = st;
        cnttot[i] = tot;
        int acc = st;
#pragma unroll
        for (int x = 0; x < 8; ++x) {
            base8[(size_t)x * NDST_TOTAL + i] = acc;
            acc += c[x];
        }
    }
}

// ============ scatter: atomic-free, 16 edges/thread ========================
__global__ __launch_bounds__(256) void scatterrank5_kernel(
    const int* __restrict__ e0, const int* __restrict__ e1,
    const int* __restrict__ e2, const int* __restrict__ e3,
    const int* __restrict__ e4, const int* __restrict__ base8,
    const int* __restrict__ rank, int* __restrict__ perm)
{
    const int type = blockIdx.x / BPT16;
    const int* ei = type == 0 ? e0 : type == 1 ? e1 : type == 2 ? e2
                  : type == 3 ? e3 : e4;
    const int b = type == 0 ? 0 : type == 1 ? 50000 : type == 2 ? 100000
                : type == 3 ? 200000 : 250000;
    int e = ((blockIdx.x % BPT16) * 256 + threadIdx.x) * 16;
    if (e >= NE) return;
    const int* rp = &rank[(size_t)type * NE + e];
#pragma unroll
    for (int u = 0; u < 4; ++u) {
        int4 s = *(const int4*)&ei[e + u * 4];
        int4 d = *(const int4*)&ei[NE + e + u * 4];
        int4 r = *(const int4*)(rp + u * 4);
        int p0 = base8[(size_t)((unsigned)r.x >> 24) * NDST_TOTAL + b + d.x] + (r.x & 0xFFFFFF);
        int p1 = base8[(size_t)((unsigned)r.y >> 24) * NDST_TOTAL + b + d.y] + (r.y & 0xFFFFFF);
        int p2 = base8[(size_t)((unsigned)r.z >> 24) * NDST_TOTAL + b + d.z] + (r.z & 0xFFFFFF);
        int p3 = base8[(size_t)((unsigned)r.w >> 24) * NDST_TOTAL + b + d.w] + (r.w & 0xFFFFFF);
        perm[p0] = s.x;
        perm[p1] = s.y;
        perm[p2] = s.z;
        perm[p3] = s.w;
    }
}

// ============ fused aggregation: fp8 rows (1 line/edge), 8 edges/iter ======
__global__ __launch_bounds__(256) void agg_all_kernel(
    const int* __restrict__ perm, const int* __restrict__ start,
    const int* __restrict__ cnttot,
    const unsigned* __restrict__ h8_ing, const unsigned* __restrict__ h8_dir,
    const float* __restrict__ s_ing, const float* __restrict__ s_dir,
    const float* __restrict__ Wk, const float* __restrict__ bk,
    float* __restrict__ pool_ing, float* __restrict__ pool_dir,
    float* __restrict__ sem_dir)
{
    __shared__ float sWk[64 * 64];
    __shared__ float srow[4][64];
    __shared__ float sred[4][64];
    const int t = threadIdx.x & 63, w = threadIdx.x >> 6;
    const int g  = t >> 4;       // edge group 0..3
    const int l4 = t & 15;       // feature quad: 4*l4 .. 4*l4+3
    const int hq = l4 >> 2;      // head of my features
    for (int i = threadIdx.x; i < 4096; i += 256) sWk[i] = Wk[i];
    const float bkf = bk[t];
    float p_ing = 0.f;
    float p0 = 0.f, p1 = 0.f, p2 = 0.f, p3 = 0.f;
    float m0 = 0.f, m1 = 0.f, m2 = 0.f, m3 = 0.f;
    __syncthreads();
    const int nwaves = gridDim.x * 4;
    for (int d = blockIdx.x * 4 + w; d < NDST_TOTAL; d += nwaves) {
        int type, ld;
        const float *ssrc, *sdst;
        const unsigned* hsrc;
        int ss, soff, ds, doff;
        if (d < 50000)       { type = 0; ld = d;          ssrc = s_ing; ss = 12; soff = 0;  sdst = s_dir; ds = 28; doff = 0;  hsrc = h8_ing; }
        else if (d < 100000) { type = 1; ld = d - 50000;  ssrc = s_ing; ss = 12; soff = 4;  sdst = s_dir; ds = 28; doff = 4;  hsrc = h8_ing; }
        else if (d < 200000) { type = 2; ld = d - 100000; ssrc = s_dir; ss = 28; soff = 8;  sdst = s_ing; ds = 12; doff = 8;  hsrc = h8_dir; }
        else if (d < 250000) { type = 3; ld = d - 200000; ssrc = s_dir; ss = 28; soff = 12; sdst = s_dir; ds = 28; doff = 16; hsrc = h8_dir; }
        else                 { type = 4; ld = d - 250000; ssrc = s_dir; ss = 28; soff = 20; sdst = s_dir; ds = 28; doff = 24; hsrc = h8_dir; }
        float adst = sdst[(size_t)ld * ds + doff + hq];
        int jb = start[d], je = jb + cnttot[d];
        float4 acc = make_float4(0.f, 0.f, 0.f, 0.f);
        float dsum = 0.f;
        for (int j = jb; j < je; j += 8) {
            int j0 = j + g, j1 = j + 4 + g;
            bool v0 = j0 < je, v1 = j1 < je;
            int s0 = perm[v0 ? j0 : je - 1];
            int s1 = perm[v1 ? j1 : je - 1];
            float c0 = ssrc[(size_t)s0 * ss + soff + hq];
            float c1 = ssrc[(size_t)s1 * ss + soff + hq];
            unsigned u0 = hsrc[(size_t)s0 * 16 + l4];
            unsigned u1 = hsrc[(size_t)s1 * 16 + l4];
            float a0 = c0 + adst; a0 = a0 > 0.f ? a0 : 0.2f * a0;
            float a1 = c1 + adst; a1 = a1 > 0.f ? a1 : 0.2f * a1;
            float e0 = v0 ? __expf(a0) : 0.f;
            float e1 = v1 ? __expf(a1) : 0.f;
            dsum += e0 + e1;
            v2f lo0 = __builtin_amdgcn_cvt_pk_f32_fp8((int)u0, false);
            v2f hi0 = __builtin_amdgcn_cvt_pk_f32_fp8((int)u0, true);
            v2f lo1 = __builtin_amdgcn_cvt_pk_f32_fp8((int)u1, false);
            v2f hi1 = __builtin_amdgcn_cvt_pk_f32_fp8((int)u1, true);
            acc.x += lo0.x * e0 + lo1.x * e1;
            acc.y += lo0.y * e0 + lo1.y * e1;
            acc.z += hi0.x * e0 + hi1.x * e1;
            acc.w += hi0.y * e0 + hi1.y * e1;
        }
#pragma unroll
        for (int mask = 16; mask <= 32; mask <<= 1) {
            acc.x += __shfl_xor(acc.x, mask, 64);
            acc.y += __shfl_xor(acc.y, mask, 64);
            acc.z += __shfl_xor(acc.z, mask, 64);
            acc.w += __shfl_xor(acc.w, mask, 64);
            dsum  += __shfl_xor(dsum,  mask, 64);
        }
        float inv = 1.f / (dsum + 1e-16f);
        float4 v4 = make_float4(fmaxf(acc.x * inv, 0.f), fmaxf(acc.y * inv, 0.f),
                                fmaxf(acc.z * inv, 0.f), fmaxf(acc.w * inv, 0.f));
        if (g == 0) *(float4*)&srow[w][l4 * 4] = v4;  // rebroadcast layout
        float v = srow[w][t];                          // wave-coherent LDS
        if (type == 2) {
            p_ing += v;
        } else {
            float a2 = bkf;
#pragma unroll
            for (int k = 0; k < 64; ++k) a2 += srow[w][k] * sWk[k * 64 + t];
            float tv = tanhf(a2);
            if (type == 0)      { p0 += v; m0 += tv; }
            else if (type == 1) { p1 += v; m1 += tv; }
            else if (type == 3) { p2 += v; m2 += tv; }
            else                { p3 += v; m3 += tv; }
        }
    }
    float vals[9] = { p_ing, p0, p1, p2, p3, m0, m1, m2, m3 };
    float* outs[9] = { pool_ing, pool_dir, pool_dir + 64, pool_dir + 128,
                       pool_dir + 192, sem_dir, sem_dir + 64, sem_dir + 128,
                       sem_dir + 192 };
    for (int i = 0; i < 9; ++i) {
        __syncthreads();
        sred[w][t] = vals[i];
        __syncthreads();
        if (w == 0)
            atomicAdd(&outs[i][t], sred[0][t] + sred[1][t] + sred[2][t] + sred[3][t]);
    }
}

// ============ final: semantic softmax + pools + VAE head ===================
__global__ __launch_bounds__(64) void final_kernel(
    const float* __restrict__ pool_ing, const float* __restrict__ pool_dir,
    const float* __restrict__ sem_dir, const float* __restrict__ q,
    const float* __restrict__ cond, const float* __restrict__ eps,
    const float* __restrict__ W_mu, const float* __restrict__ b_mu,
    const float* __restrict__ W_lv, const float* __restrict__ b_lv,
    const float* __restrict__ W_fc3, const float* __restrict__ b_fc3,
    const float* __restrict__ W_fc2, const float* __restrict__ b_fc2,
    float* __restrict__ out)
{
    __shared__ float gr[136];
    __shared__ float sc[4], attn[4];
    __shared__ float z[32], hfc[64];
    int t = threadIdx.x;  // 64 threads
    if (t < 4) {
        float s = 0.f;
        for (int f = 0; f < 64; ++f)
            s += (sem_dir[t * 64 + f] / (float)N_DIR) * q[f];
        sc[t] = s;
    }
    gr[t] = pool_ing[t] / (float)N_ING;   // out_ing == o_cont (T=1 softmax)
    __syncthreads();
    if (t == 0) {
        float m = fmaxf(fmaxf(sc[0], sc[1]), fmaxf(sc[2], sc[3]));
        float ssum = 0.f;
        for (int i = 0; i < 4; ++i) { attn[i] = expf(sc[i] - m); ssum += attn[i]; }
        for (int i = 0; i < 4; ++i) attn[i] /= ssum;
    }
    __syncthreads();
    {
        float v = 0.f;
        for (int tt = 0; tt < 4; ++tt)
            v += attn[tt] * (pool_dir[tt * 64 + t] / (float)N_DIR);
        gr[64 + t] = v;
    }
    if (t < 8) gr[128 + t] = cond[t];
    __syncthreads();
    if (t < 32) {
        float m = b_mu[t], lv = b_lv[t];
        for (int i = 0; i < 136; ++i) {
            float g = gr[i];
            m  += g * W_mu[i * 32 + t];
            lv += g * W_lv[i * 32 + t];
        }
        out[16 + t] = m;
        out[48 + t] = lv;
        z[t] = m + eps[t] * expf(0.5f * lv);
    }
    __syncthreads();
    {
        float v = b_fc3[t];
        for (int j = 0; j < 32; ++j) v += z[j] * W_fc3[j * 64 + t];
        hfc[t] = fmaxf(v, 0.f);
    }
    __syncthreads();
    if (t < 16) {
        float v = b_fc2[t];
        for (int f = 0; f < 64; ++f) v += hfc[f] * W_fc2[f * 16 + t];
        out[t] = tanhf(v);
    }
}

extern "C" void kernel_launch(void* const* d_in, const int* in_sizes, int n_in,
                              void* d_out, int out_size, void* d_ws, size_t ws_size,
                              hipStream_t stream) {
    const float* x_ing = (const float*)d_in[0];
    const float* x_dir = (const float*)d_in[1];
    const float* cond  = (const float*)d_in[2];
    const float* eps   = (const float*)d_in[3];
    const int* ei_cooc     = (const int*)d_in[4];
    const int* ei_used     = (const int*)d_in[5];
    const int* ei_contains = (const int*)d_in[6];
    const int* ei_pairs    = (const int*)d_in[7];
    const int* ei_follows  = (const int*)d_in[8];
    const float* W_pi = (const float*)d_in[9];
    const float* b_pi = (const float*)d_in[10];
    const float* W_pd = (const float*)d_in[11];
    const float* b_pd = (const float*)d_in[12];
    const float* Wk   = (const float*)d_in[13];
    const float* bk   = (const float*)d_in[14];
    const float* q    = (const float*)d_in[15];
    const float* W_mu = (const float*)d_in[16];
    const float* b_mu = (const float*)d_in[17];
    const float* W_lv = (const float*)d_in[18];
    const float* b_lv = (const float*)d_in[19];
    const float* W_fc3 = (const float*)d_in[20];
    const float* b_fc3 = (const float*)d_in[21];
    const float* W_fc2 = (const float*)d_in[22];
    const float* b_fc2 = (const float*)d_in[23];
    const float* as_cooc     = (const float*)d_in[24];
    const float* ad_cooc     = (const float*)d_in[25];
    const float* as_used     = (const float*)d_in[26];
    const float* ad_used     = (const float*)d_in[27];
    const float* as_contains = (const float*)d_in[28];
    const float* ad_contains = (const float*)d_in[29];
    const float* as_pairs    = (const float*)d_in[30];
    const float* ad_pairs    = (const float*)d_in[31];
    const float* as_follows  = (const float*)d_in[32];
    const float* ad_follows  = (const float*)d_in[33];

    // ---- workspace layout ----
    unsigned* h8_ing = (unsigned*)d_ws;                       // N_ING*16 u32 (fp8x4)
    unsigned* h8_dir = h8_ing + (size_t)N_ING * 16;           // N_DIR*16
    float* s_ing = (float*)(h8_dir + (size_t)N_DIR * 16);     // N_ING*12 fp32
    float* s_dir = s_ing + (size_t)N_ING * 12;                // N_DIR*28 fp32
    int*   perm   = (int*)(s_dir + (size_t)N_DIR * 28);       // 5M
    int*   rank   = perm + (size_t)5 * NE;                    // 5M
    int*   start  = rank + (size_t)5 * NE;                    // 300K
    int*   cnttot = start + NDST_TOTAL;                       // 300K
    int*   base8  = cnttot + NDST_TOTAL;                      // 8*300K
    int*   cnt8   = base8 + (size_t)8 * NDST_TOTAL;           // 8*300K (zeroed)
    int*   cursor = cnt8 + (size_t)8 * NDST_TOTAL;            // 1
    float* pool_ing = (float*)(cursor + 1);                   // 64
    float* pool_dir = pool_ing + 64;                          // 4*64
    float* sem_dir  = pool_dir + 256;                         // 4*64

    // single memset: cnt8 + cursor + pools (contiguous)
    hipMemsetAsync(cnt8, 0,
        ((size_t)8 * NDST_TOTAL + 1 + 64 + 256 + 256) * sizeof(int), stream);

    // K1: histrank (XCD-local atomics) + fused proj/fp8/score for both types
    mega_kernel<<<NBH + NB_ING + NB_DIR, 256, 0, stream>>>(
        ei_cooc, ei_used, ei_contains, ei_pairs, ei_follows, cnt8, rank,
        x_ing, W_pi, b_pi, as_cooc, as_used, ad_contains, h8_ing, s_ing,
        x_dir, W_pd, b_pd, ad_cooc, ad_used, as_contains, as_pairs, ad_pairs,
        as_follows, ad_follows, h8_dir, s_dir);

    offsets_kernel<<<(NDST_TOTAL + 255) / 256, 256, 0, stream>>>(
        cnt8, start, cnttot, base8, cursor);

    scatterrank5_kernel<<<NBH, 256, 0, stream>>>(
        ei_cooc, ei_used, ei_contains, ei_pairs, ei_follows, base8, rank, perm);

    agg_all_kernel<<<2048, 256, 0, stream>>>(
        perm, start, cnttot, h8_ing, h8_dir, s_ing, s_dir, Wk, bk,
        pool_ing, pool_dir, sem_dir);

    final_kernel<<<1, 64, 0, stream>>>(
        pool_ing, pool_dir, sem_dir, q, cond, eps,
        W_mu, b_mu, W_lv, b_lv, W_fc3, b_fc3, W_fc2, b_fc2, (float*)d_out);
}

// Round 8
// 567.977 us; speedup vs baseline: 4.7060x; 1.2069x over previous
//
#include <hip/hip_runtime.h>
#include <math.h>

#define N_ING 100000
#define N_DIR 50000
#define NE    1000000
#define NDST_TOTAL 300000   // 50K(cooc)+50K(used)+100K(contains)+50K(pairs)+50K(follows)
#define NBUCK 4688          // ceil(300000/64): 64 dst nodes per bucket
#define BA    64            // hist/scatter blocks per edge type
#define NBLK_A (5 * BA)     // 320
#define I4PT  (NE / 4)      // int4s per type
#define PB_ING 192
#define PB_DIR 96

typedef float v2f __attribute__((ext_vector_type(2)));

// ============ K1: bucket histogram (LDS atomics only) + fused proj+score ===
__global__ __launch_bounds__(256) void k1_kernel(
    const int* __restrict__ e0, const int* __restrict__ e1,
    const int* __restrict__ e2, const int* __restrict__ e3,
    const int* __restrict__ e4, int* __restrict__ blockcnt,
    const float* __restrict__ x_ing, const float* __restrict__ W_pi,
    const float* __restrict__ b_pi,
    const float* __restrict__ as_cooc, const float* __restrict__ as_used,
    const float* __restrict__ ad_contains,
    unsigned* __restrict__ h8_ing, float* __restrict__ s_ing,
    const float* __restrict__ x_dir, const float* __restrict__ W_pd,
    const float* __restrict__ b_pd,
    const float* __restrict__ ad_cooc, const float* __restrict__ ad_used,
    const float* __restrict__ as_contains, const float* __restrict__ as_pairs,
    const float* __restrict__ ad_pairs, const float* __restrict__ as_follows,
    const float* __restrict__ ad_follows,
    unsigned* __restrict__ h8_dir, float* __restrict__ s_dir)
{
    __shared__ int hist[NBUCK];
    __shared__ float sW[16 * 64];
    __shared__ float sbb[64];
    __shared__ float satt[7 * 64];
    __shared__ float sx[4][16];
    __shared__ float srow[4][64];

    const int bid = blockIdx.x;
    const int tid = threadIdx.x;
    if (bid < NBLK_A) {
        // ---------- bucket histogram, one row per block ----------
        const int type = bid >> 6, blk = bid & 63;
        const int* ei = type == 0 ? e0 : type == 1 ? e1 : type == 2 ? e2
                      : type == 3 ? e3 : e4;
        const int base = type == 0 ? 0 : type == 1 ? 50000 : type == 2 ? 100000
                       : type == 3 ? 200000 : 250000;
        for (int i = tid; i < NBUCK; i += 256) hist[i] = 0;
        __syncthreads();
        const int4* d4 = (const int4*)(ei + NE);
        for (int i = blk * 256 + tid; i < I4PT; i += BA * 256) {
            int4 d = d4[i];
            atomicAdd(&hist[(base + d.x) >> 6], 1);
            atomicAdd(&hist[(base + d.y) >> 6], 1);
            atomicAdd(&hist[(base + d.z) >> 6], 1);
            atomicAdd(&hist[(base + d.w) >> 6], 1);
        }
        __syncthreads();
        int* row = blockcnt + (size_t)bid * NBUCK;
        for (int i = tid; i < NBUCK; i += 256) row[i] = hist[i];
    } else if (bid < NBLK_A + PB_ING) {
        // ---------- proj + fp8 pack + scores, ingredient nodes ----------
        const int g = tid >> 6, t = tid & 63;
        for (int i = tid; i < 16 * 64; i += 256) sW[i] = W_pi[i];
        if (tid < 64) {
            sbb[tid] = b_pi[tid];
            satt[tid]       = as_cooc[tid];
            satt[64 + tid]  = as_used[tid];
            satt[128 + tid] = ad_contains[tid];
        }
        __syncthreads();
        for (int q = bid - NBLK_A; q < N_ING / 4; q += PB_ING) {
            int n = q * 4 + g;
            if (t < 16) sx[g][t] = x_ing[(size_t)n * 16 + t];
            __syncthreads();
            float s = sbb[t];
#pragma unroll
            for (int i = 0; i < 16; ++i) s += sx[g][i] * sW[i * 64 + t];
            srow[g][t] = s;
            __syncthreads();
            if (t < 16) {
                int w0 = __builtin_amdgcn_cvt_pk_fp8_f32(srow[g][t * 4], srow[g][t * 4 + 1], 0, false);
                int w  = __builtin_amdgcn_cvt_pk_fp8_f32(srow[g][t * 4 + 2], srow[g][t * 4 + 3], w0, true);
                h8_ing[(size_t)n * 16 + t] = (unsigned)w;
            }
            if (t < 12) {
                int slot = t >> 2, hh = t & 3;
                float sc = 0.f;
#pragma unroll
                for (int d = 0; d < 16; ++d)
                    sc += srow[g][hh * 16 + d] * satt[slot * 64 + hh * 16 + d];
                s_ing[(size_t)n * 12 + t] = sc;
            }
            __syncthreads();
        }
    } else {
        // ---------- proj + fp8 pack + scores, direction nodes ----------
        const int g = tid >> 6, t = tid & 63;
        for (int i = tid; i < 8 * 64; i += 256) sW[i] = W_pd[i];
        if (tid < 64) {
            sbb[tid] = b_pd[tid];
            satt[tid]        = ad_cooc[tid];
            satt[64  + tid]  = ad_used[tid];
            satt[128 + tid]  = as_contains[tid];
            satt[192 + tid]  = as_pairs[tid];
            satt[256 + tid]  = ad_pairs[tid];
            satt[320 + tid]  = as_follows[tid];
            satt[384 + tid]  = ad_follows[tid];
        }
        __syncthreads();
        for (int q = bid - NBLK_A - PB_ING; q < N_DIR / 4; q += PB_DIR) {
            int n = q * 4 + g;
            if (t < 8) sx[g][t] = x_dir[(size_t)n * 8 + t];
            __syncthreads();
            float s = sbb[t];
#pragma unroll
            for (int i = 0; i < 8; ++i) s += sx[g][i] * sW[i * 64 + t];
            srow[g][t] = s;
            __syncthreads();
            if (t < 16) {
                int w0 = __builtin_amdgcn_cvt_pk_fp8_f32(srow[g][t * 4], srow[g][t * 4 + 1], 0, false);
                int w  = __builtin_amdgcn_cvt_pk_fp8_f32(srow[g][t * 4 + 2], srow[g][t * 4 + 3], w0, true);
                h8_dir[(size_t)n * 16 + t] = (unsigned)w;
            }
            if (t < 28) {
                int slot = t >> 2, hh = t & 3;
                float sc = 0.f;
#pragma unroll
                for (int d = 0; d < 16; ++d)
                    sc += srow[g][hh * 16 + d] * satt[slot * 64 + hh * 16 + d];
                s_dir[(size_t)n * 28 + t] = sc;
            }
            __syncthreads();
        }
    }
}

// ============ K2: bucket totals + bases + per-(block,bucket) bases =========
__global__ __launch_bounds__(256) void k2_kernel(
    const int* __restrict__ blockcnt, int* __restrict__ blockbase,
    int* __restrict__ bbase, int* __restrict__ btot, int* __restrict__ cursor)
{
    __shared__ int sh[256];
    __shared__ int bw;
    int b = blockIdx.x * 256 + threadIdx.x;
    bool act = b < NBUCK;
    int tot = 0;
    if (act)
        for (int k = 0; k < NBLK_A; ++k) tot += blockcnt[(size_t)k * NBUCK + b];
    sh[threadIdx.x] = tot;
    __syncthreads();
    for (int off = 1; off < 256; off <<= 1) {
        int v = (threadIdx.x >= off) ? sh[threadIdx.x - off] : 0;
        __syncthreads();
        sh[threadIdx.x] += v;
        __syncthreads();
    }
    if (threadIdx.x == 255) bw = atomicAdd(cursor, sh[255]);
    __syncthreads();
    if (act) {
        int base = bw + sh[threadIdx.x] - tot;  // exclusive
        bbase[b] = base;
        btot[b] = tot;
        int run = base;
        for (int k = 0; k < NBLK_A; ++k) {
            int c = blockcnt[(size_t)k * NBUCK + b];
            blockbase[(size_t)k * NBUCK + b] = run;
            run += c;
        }
    }
}

// ============ K3: bucket scatter (LDS cursors, zero global atomics) ========
__global__ __launch_bounds__(256) void k3_kernel(
    const int* __restrict__ e0, const int* __restrict__ e1,
    const int* __restrict__ e2, const int* __restrict__ e3,
    const int* __restrict__ e4, const int* __restrict__ blockbase,
    int2* __restrict__ bpair)
{
    __shared__ int cur[NBUCK];
    const int bid = blockIdx.x, tid = threadIdx.x;
    const int type = bid >> 6, blk = bid & 63;
    const int* ei = type == 0 ? e0 : type == 1 ? e1 : type == 2 ? e2
                  : type == 3 ? e3 : e4;
    const int base = type == 0 ? 0 : type == 1 ? 50000 : type == 2 ? 100000
                   : type == 3 ? 200000 : 250000;
    const int* row = blockbase + (size_t)bid * NBUCK;
    for (int i = tid; i < NBUCK; i += 256) cur[i] = row[i];
    __syncthreads();
    const int4* s4 = (const int4*)ei;
    const int4* d4 = (const int4*)(ei + NE);
    for (int i = blk * 256 + tid; i < I4PT; i += BA * 256) {
        int4 s = s4[i];
        int4 d = d4[i];
        int g0 = base + d.x, g1 = base + d.y, g2 = base + d.z, g3 = base + d.w;
        int p0 = atomicAdd(&cur[g0 >> 6], 1);
        int p1 = atomicAdd(&cur[g1 >> 6], 1);
        int p2 = atomicAdd(&cur[g2 >> 6], 1);
        int p3 = atomicAdd(&cur[g3 >> 6], 1);
        bpair[p0] = make_int2(s.x, g0);
        bpair[p1] = make_int2(s.y, g1);
        bpair[p2] = make_int2(s.z, g2);
        bpair[p3] = make_int2(s.w, g3);
    }
}

// ============ K4: per-bucket counting sort -> perm + start/cnt =============
__global__ __launch_bounds__(256) void k4_kernel(
    const int2* __restrict__ bpair, const int* __restrict__ bbase,
    const int* __restrict__ btot, int* __restrict__ perm,
    int* __restrict__ start, int* __restrict__ cnt)
{
    __shared__ int h[64], sc[64], cu[64];
    const int b = blockIdx.x, tid = threadIdx.x;
    const int jb = bbase[b], n = btot[b];
    if (tid < 64) h[tid] = 0;
    __syncthreads();
    for (int i = tid; i < n; i += 256)
        atomicAdd(&h[bpair[jb + i].y & 63], 1);
    __syncthreads();
    if (tid == 0) {
        int r = 0;
        for (int i = 0; i < 64; ++i) { sc[i] = r; cu[i] = r; r += h[i]; }
    }
    __syncthreads();
    if (tid < 64) {
        int dg = b * 64 + tid;
        if (dg < NDST_TOTAL) {
            start[dg] = jb + sc[tid];
            cnt[dg] = h[tid];
        }
    }
    for (int i = tid; i < n; i += 256) {
        int2 p = bpair[jb + i];
        int pos = atomicAdd(&cu[p.y & 63], 1);
        perm[jb + pos] = p.x;
    }
}

// ============ fused aggregation: fp8 rows (1 line/edge), 8 edges/iter ======
__global__ __launch_bounds__(256) void agg_all_kernel(
    const int* __restrict__ perm, const int* __restrict__ start,
    const int* __restrict__ cnttot,
    const unsigned* __restrict__ h8_ing, const unsigned* __restrict__ h8_dir,
    const float* __restrict__ s_ing, const float* __restrict__ s_dir,
    const float* __restrict__ Wk, const float* __restrict__ bk,
    float* __restrict__ pool_ing, float* __restrict__ pool_dir,
    float* __restrict__ sem_dir)
{
    __shared__ float sWk[64 * 64];
    __shared__ float srow[4][64];
    __shared__ float sred[4][64];
    const int t = threadIdx.x & 63, w = threadIdx.x >> 6;
    const int g  = t >> 4;       // edge group 0..3
    const int l4 = t & 15;       // feature quad: 4*l4 .. 4*l4+3
    const int hq = l4 >> 2;      // head of my features
    for (int i = threadIdx.x; i < 4096; i += 256) sWk[i] = Wk[i];
    const float bkf = bk[t];
    float p_ing = 0.f;
    float p0 = 0.f, p1 = 0.f, p2 = 0.f, p3 = 0.f;
    float m0 = 0.f, m1 = 0.f, m2 = 0.f, m3 = 0.f;
    __syncthreads();
    const int nwaves = gridDim.x * 4;
    for (int d = blockIdx.x * 4 + w; d < NDST_TOTAL; d += nwaves) {
        int type, ld;
        const float *ssrc, *sdst;
        const unsigned* hsrc;
        int ss, soff, ds, doff;
        if (d < 50000)       { type = 0; ld = d;          ssrc = s_ing; ss = 12; soff = 0;  sdst = s_dir; ds = 28; doff = 0;  hsrc = h8_ing; }
        else if (d < 100000) { type = 1; ld = d - 50000;  ssrc = s_ing; ss = 12; soff = 4;  sdst = s_dir; ds = 28; doff = 4;  hsrc = h8_ing; }
        else if (d < 200000) { type = 2; ld = d - 100000; ssrc = s_dir; ss = 28; soff = 8;  sdst = s_ing; ds = 12; doff = 8;  hsrc = h8_dir; }
        else if (d < 250000) { type = 3; ld = d - 200000; ssrc = s_dir; ss = 28; soff = 12; sdst = s_dir; ds = 28; doff = 16; hsrc = h8_dir; }
        else                 { type = 4; ld = d - 250000; ssrc = s_dir; ss = 28; soff = 20; sdst = s_dir; ds = 28; doff = 24; hsrc = h8_dir; }
        float adst = sdst[(size_t)ld * ds + doff + hq];
        int jb = start[d], je = jb + cnttot[d];
        float4 acc = make_float4(0.f, 0.f, 0.f, 0.f);
        float dsum = 0.f;
        for (int j = jb; j < je; j += 8) {
            int j0 = j + g, j1 = j + 4 + g;
            bool v0 = j0 < je, v1 = j1 < je;
            int s0 = perm[v0 ? j0 : je - 1];
            int s1 = perm[v1 ? j1 : je - 1];
            float c0 = ssrc[(size_t)s0 * ss + soff + hq];
            float c1 = ssrc[(size_t)s1 * ss + soff + hq];
            unsigned u0 = hsrc[(size_t)s0 * 16 + l4];
            unsigned u1 = hsrc[(size_t)s1 * 16 + l4];
            float a0 = c0 + adst; a0 = a0 > 0.f ? a0 : 0.2f * a0;
            float a1 = c1 + adst; a1 = a1 > 0.f ? a1 : 0.2f * a1;
            float e0 = v0 ? __expf(a0) : 0.f;
            float e1 = v1 ? __expf(a1) : 0.f;
            dsum += e0 + e1;
            v2f lo0 = __builtin_amdgcn_cvt_pk_f32_fp8((int)u0, false);
            v2f hi0 = __builtin_amdgcn_cvt_pk_f32_fp8((int)u0, true);
            v2f lo1 = __builtin_amdgcn_cvt_pk_f32_fp8((int)u1, false);
            v2f hi1 = __builtin_amdgcn_cvt_pk_f32_fp8((int)u1, true);
            acc.x += lo0.x * e0 + lo1.x * e1;
            acc.y += lo0.y * e0 + lo1.y * e1;
            acc.z += hi0.x * e0 + hi1.x * e1;
            acc.w += hi0.y * e0 + hi1.y * e1;
        }
#pragma unroll
        for (int mask = 16; mask <= 32; mask <<= 1) {
            acc.x += __shfl_xor(acc.x, mask, 64);
            acc.y += __shfl_xor(acc.y, mask, 64);
            acc.z += __shfl_xor(acc.z, mask, 64);
            acc.w += __shfl_xor(acc.w, mask, 64);
            dsum  += __shfl_xor(dsum,  mask, 64);
        }
        float inv = 1.f / (dsum + 1e-16f);
        float4 v4 = make_float4(fmaxf(acc.x * inv, 0.f), fmaxf(acc.y * inv, 0.f),
                                fmaxf(acc.z * inv, 0.f), fmaxf(acc.w * inv, 0.f));
        if (g == 0) *(float4*)&srow[w][l4 * 4] = v4;  // rebroadcast layout
        float v = srow[w][t];                          // wave-coherent LDS
        if (type == 2) {
            p_ing += v;
        } else {
            float a2 = bkf;
#pragma unroll
            for (int k = 0; k < 64; ++k) a2 += srow[w][k] * sWk[k * 64 + t];
            float tv = tanhf(a2);
            if (type == 0)      { p0 += v; m0 += tv; }
            else if (type == 1) { p1 += v; m1 += tv; }
            else if (type == 3) { p2 += v; m2 += tv; }
            else                { p3 += v; m3 += tv; }
        }
    }
    float vals[9] = { p_ing, p0, p1, p2, p3, m0, m1, m2, m3 };
    float* outs[9] = { pool_ing, pool_dir, pool_dir + 64, pool_dir + 128,
                       pool_dir + 192, sem_dir, sem_dir + 64, sem_dir + 128,
                       sem_dir + 192 };
    for (int i = 0; i < 9; ++i) {
        __syncthreads();
        sred[w][t] = vals[i];
        __syncthreads();
        if (w == 0)
            atomicAdd(&outs[i][t], sred[0][t] + sred[1][t] + sred[2][t] + sred[3][t]);
    }
}

// ============ final: semantic softmax + pools + VAE head ===================
__global__ __launch_bounds__(64) void final_kernel(
    const float* __restrict__ pool_ing, const float* __restrict__ pool_dir,
    const float* __restrict__ sem_dir, const float* __restrict__ q,
    const float* __restrict__ cond, const float* __restrict__ eps,
    const float* __restrict__ W_mu, const float* __restrict__ b_mu,
    const float* __restrict__ W_lv, const float* __restrict__ b_lv,
    const float* __restrict__ W_fc3, const float* __restrict__ b_fc3,
    const float* __restrict__ W_fc2, const float* __restrict__ b_fc2,
    float* __restrict__ out)
{
    __shared__ float gr[136];
    __shared__ float sc[4], attn[4];
    __shared__ float z[32], hfc[64];
    int t = threadIdx.x;  // 64 threads
    if (t < 4) {
        float s = 0.f;
        for (int f = 0; f < 64; ++f)
            s += (sem_dir[t * 64 + f] / (float)N_DIR) * q[f];
        sc[t] = s;
    }
    gr[t] = pool_ing[t] / (float)N_ING;   // out_ing == o_cont (T=1 softmax)
    __syncthreads();
    if (t == 0) {
        float m = fmaxf(fmaxf(sc[0], sc[1]), fmaxf(sc[2], sc[3]));
        float ssum = 0.f;
        for (int i = 0; i < 4; ++i) { attn[i] = expf(sc[i] - m); ssum += attn[i]; }
        for (int i = 0; i < 4; ++i) attn[i] /= ssum;
    }
    __syncthreads();
    {
        float v = 0.f;
        for (int tt = 0; tt < 4; ++tt)
            v += attn[tt] * (pool_dir[tt * 64 + t] / (float)N_DIR);
        gr[64 + t] = v;
    }
    if (t < 8) gr[128 + t] = cond[t];
    __syncthreads();
    if (t < 32) {
        float m = b_mu[t], lv = b_lv[t];
        for (int i = 0; i < 136; ++i) {
            float g = gr[i];
            m  += g * W_mu[i * 32 + t];
            lv += g * W_lv[i * 32 + t];
        }
        out[16 + t] = m;
        out[48 + t] = lv;
        z[t] = m + eps[t] * expf(0.5f * lv);
    }
    __syncthreads();
    {
        float v = b_fc3[t];
        for (int j = 0; j < 32; ++j) v += z[j] * W_fc3[j * 64 + t];
        hfc[t] = fmaxf(v, 0.f);
    }
    __syncthreads();
    if (t < 16) {
        float v = b_fc2[t];
        for (int f = 0; f < 64; ++f) v += hfc[f] * W_fc2[f * 16 + t];
        out[t] = tanhf(v);
    }
}

extern "C" void kernel_launch(void* const* d_in, const int* in_sizes, int n_in,
                              void* d_out, int out_size, void* d_ws, size_t ws_size,
                              hipStream_t stream) {
    const float* x_ing = (const float*)d_in[0];
    const float* x_dir = (const float*)d_in[1];
    const float* cond  = (const float*)d_in[2];
    const float* eps   = (const float*)d_in[3];
    const int* ei_cooc     = (const int*)d_in[4];
    const int* ei_used     = (const int*)d_in[5];
    const int* ei_contains = (const int*)d_in[6];
    const int* ei_pairs    = (const int*)d_in[7];
    const int* ei_follows  = (const int*)d_in[8];
    const float* W_pi = (const float*)d_in[9];
    const float* b_pi = (const float*)d_in[10];
    const float* W_pd = (const float*)d_in[11];
    const float* b_pd = (const float*)d_in[12];
    const float* Wk   = (const float*)d_in[13];
    const float* bk   = (const float*)d_in[14];
    const float* q    = (const float*)d_in[15];
    const float* W_mu = (const float*)d_in[16];
    const float* b_mu = (const float*)d_in[17];
    const float* W_lv = (const float*)d_in[18];
    const float* b_lv = (const float*)d_in[19];
    const float* W_fc3 = (const float*)d_in[20];
    const float* b_fc3 = (const float*)d_in[21];
    const float* W_fc2 = (const float*)d_in[22];
    const float* b_fc2 = (const float*)d_in[23];
    const float* as_cooc     = (const float*)d_in[24];
    const float* ad_cooc     = (const float*)d_in[25];
    const float* as_used     = (const float*)d_in[26];
    const float* ad_used     = (const float*)d_in[27];
    const float* as_contains = (const float*)d_in[28];
    const float* ad_contains = (const float*)d_in[29];
    const float* as_pairs    = (const float*)d_in[30];
    const float* ad_pairs    = (const float*)d_in[31];
    const float* as_follows  = (const float*)d_in[32];
    const float* ad_follows  = (const float*)d_in[33];

    // ---- workspace layout (16 B-aligned chunks) ----
    int2* bpair = (int2*)d_ws;                                // 5M int2 = 40 MB
    unsigned* h8_ing = (unsigned*)(bpair + (size_t)5 * NE);   // N_ING*16 u32
    unsigned* h8_dir = h8_ing + (size_t)N_ING * 16;           // N_DIR*16
    float* s_ing = (float*)(h8_dir + (size_t)N_DIR * 16);     // N_ING*12 fp32
    float* s_dir = s_ing + (size_t)N_ING * 12;                // N_DIR*28 fp32
    int*   perm   = (int*)(s_dir + (size_t)N_DIR * 28);       // 5M
    int*   blockcnt  = perm + (size_t)5 * NE;                 // 320*4688
    int*   blockbase = blockcnt + (size_t)NBLK_A * NBUCK;     // 320*4688
    int*   bbase  = blockbase + (size_t)NBLK_A * NBUCK;       // 4688
    int*   btot   = bbase + NBUCK;                            // 4688
    int*   start  = btot + NBUCK;                             // 300K
    int*   cnt    = start + NDST_TOTAL;                       // 300K
    int*   cursor = cnt + NDST_TOTAL;                         // 1  (zeroed region)
    float* pool_ing = (float*)(cursor + 1);                   // 64
    float* pool_dir = pool_ing + 64;                          // 4*64
    float* sem_dir  = pool_dir + 256;                         // 4*64

    // tiny memset: cursor + pools
    hipMemsetAsync(cursor, 0, (1 + 64 + 256 + 256) * sizeof(int), stream);

    // K1: bucket histogram (LDS-only atomics) + fused proj/fp8/score
    k1_kernel<<<NBLK_A + PB_ING + PB_DIR, 256, 0, stream>>>(
        ei_cooc, ei_used, ei_contains, ei_pairs, ei_follows, blockcnt,
        x_ing, W_pi, b_pi, as_cooc, as_used, ad_contains, h8_ing, s_ing,
        x_dir, W_pd, b_pd, ad_cooc, ad_used, as_contains, as_pairs, ad_pairs,
        as_follows, ad_follows, h8_dir, s_dir);

    // K2: bucket scan -> bases
    k2_kernel<<<(NBUCK + 255) / 256, 256, 0, stream>>>(
        blockcnt, blockbase, bbase, btot, cursor);

    // K3: bucket scatter (LDS cursors)
    k3_kernel<<<NBLK_A, 256, 0, stream>>>(
        ei_cooc, ei_used, ei_contains, ei_pairs, ei_follows, blockbase, bpair);

    // K4: per-bucket counting sort -> perm + start/cnt
    k4_kernel<<<NBUCK, 256, 0, stream>>>(bpair, bbase, btot, perm, start, cnt);

    // agg over all 300K dst segments
    agg_all_kernel<<<2048, 256, 0, stream>>>(
        perm, start, cnt, h8_ing, h8_dir, s_ing, s_dir, Wk, bk,
        pool_ing, pool_dir, sem_dir);

    final_kernel<<<1, 64, 0, stream>>>(
        pool_ing, pool_dir, sem_dir, q, cond, eps,
        W_mu, b_mu, W_lv, b_lv, W_fc3, b_fc3, W_fc2, b_fc2, (float*)d_out);
}

// Round 9
// 492.804 us; speedup vs baseline: 5.4238x; 1.1525x over previous
//
#include <hip/hip_runtime.h>
#include <hip/hip_fp16.h>
#include <math.h>

#define N_ING 100000
#define N_DIR 50000
#define NE    1000000
#define NDST_TOTAL 300000   // 50K(cooc)+50K(used)+100K(contains)+50K(pairs)+50K(follows)
#define NBUCK 4688          // ceil(300000/64): 64 dst nodes per bucket
#define BA    16            // hist/scatter blocks per edge type
#define NBK   (5 * BA)      // 80
#define I4PT  (NE / 4)      // int4s per type
#define PB_ING 384
#define PB_DIR 192

typedef float v2f __attribute__((ext_vector_type(2)));

// ============ kA: bucket histogram (LDS atomics) + fused proj+score ========
__global__ __launch_bounds__(256) void kA_kernel(
    const int* __restrict__ e0, const int* __restrict__ e1,
    const int* __restrict__ e2, const int* __restrict__ e3,
    const int* __restrict__ e4, int* __restrict__ blockcnt,
    const float* __restrict__ x_ing, const float* __restrict__ W_pi,
    const float* __restrict__ b_pi,
    const float* __restrict__ as_cooc, const float* __restrict__ as_used,
    const float* __restrict__ ad_contains,
    unsigned* __restrict__ h8_ing, __half* __restrict__ s_ing,
    const float* __restrict__ x_dir, const float* __restrict__ W_pd,
    const float* __restrict__ b_pd,
    const float* __restrict__ ad_cooc, const float* __restrict__ ad_used,
    const float* __restrict__ as_contains, const float* __restrict__ as_pairs,
    const float* __restrict__ ad_pairs, const float* __restrict__ as_follows,
    const float* __restrict__ ad_follows,
    unsigned* __restrict__ h8_dir, __half* __restrict__ s_dir)
{
    __shared__ int hist[NBUCK];
    __shared__ float sW[16 * 64];
    __shared__ float sbb[64];
    __shared__ float satt[7 * 64];
    __shared__ float sx[4][16];
    __shared__ float srow[4][64];

    const int bid = blockIdx.x;
    const int tid = threadIdx.x;
    if (bid < NBK) {
        // ---------- bucket histogram, one row per block ----------
        const int type = bid / BA, blk = bid % BA;
        const int* ei = type == 0 ? e0 : type == 1 ? e1 : type == 2 ? e2
                      : type == 3 ? e3 : e4;
        const int base = type == 0 ? 0 : type == 1 ? 50000 : type == 2 ? 100000
                       : type == 3 ? 200000 : 250000;
        for (int i = tid; i < NBUCK; i += 256) hist[i] = 0;
        __syncthreads();
        const int4* d4 = (const int4*)(ei + NE);
        for (int i = blk * 256 + tid; i < I4PT; i += BA * 256) {
            int4 d = d4[i];
            atomicAdd(&hist[(base + d.x) >> 6], 1);
            atomicAdd(&hist[(base + d.y) >> 6], 1);
            atomicAdd(&hist[(base + d.z) >> 6], 1);
            atomicAdd(&hist[(base + d.w) >> 6], 1);
        }
        __syncthreads();
        int* row = blockcnt + (size_t)bid * NBUCK;
        for (int i = tid; i < NBUCK; i += 256) row[i] = hist[i];
    } else if (bid < NBK + PB_ING) {
        // ---------- proj + fp8 pack + fp16 scores, ingredient nodes ---------
        const int g = tid >> 6, t = tid & 63;
        for (int i = tid; i < 16 * 64; i += 256) sW[i] = W_pi[i];
        if (tid < 64) {
            sbb[tid] = b_pi[tid];
            satt[tid]       = as_cooc[tid];
            satt[64 + tid]  = as_used[tid];
            satt[128 + tid] = ad_contains[tid];
        }
        __syncthreads();
        for (int q = bid - NBK; q < N_ING / 4; q += PB_ING) {
            int n = q * 4 + g;
            if (t < 16) sx[g][t] = x_ing[(size_t)n * 16 + t];
            __syncthreads();
            float s = sbb[t];
#pragma unroll
            for (int i = 0; i < 16; ++i) s += sx[g][i] * sW[i * 64 + t];
            srow[g][t] = s;
            __syncthreads();
            if (t < 16) {
                int w0 = __builtin_amdgcn_cvt_pk_fp8_f32(srow[g][t * 4], srow[g][t * 4 + 1], 0, false);
                int w  = __builtin_amdgcn_cvt_pk_fp8_f32(srow[g][t * 4 + 2], srow[g][t * 4 + 3], w0, true);
                h8_ing[(size_t)n * 16 + t] = (unsigned)w;
            }
            if (t < 12) {
                int slot = t >> 2, hh = t & 3;
                float sc = 0.f;
#pragma unroll
                for (int d = 0; d < 16; ++d)
                    sc += srow[g][hh * 16 + d] * satt[slot * 64 + hh * 16 + d];
                s_ing[(size_t)n * 12 + t] = __float2half(sc);
            }
            __syncthreads();
        }
    } else {
        // ---------- proj + fp8 pack + fp16 scores, direction nodes ----------
        const int g = tid >> 6, t = tid & 63;
        for (int i = tid; i < 8 * 64; i += 256) sW[i] = W_pd[i];
        if (tid < 64) {
            sbb[tid] = b_pd[tid];
            satt[tid]        = ad_cooc[tid];
            satt[64  + tid]  = ad_used[tid];
            satt[128 + tid]  = as_contains[tid];
            satt[192 + tid]  = as_pairs[tid];
            satt[256 + tid]  = ad_pairs[tid];
            satt[320 + tid]  = as_follows[tid];
            satt[384 + tid]  = ad_follows[tid];
        }
        __syncthreads();
        for (int q = bid - NBK - PB_ING; q < N_DIR / 4; q += PB_DIR) {
            int n = q * 4 + g;
            if (t < 8) sx[g][t] = x_dir[(size_t)n * 8 + t];
            __syncthreads();
            float s = sbb[t];
#pragma unroll
            for (int i = 0; i < 8; ++i) s += sx[g][i] * sW[i * 64 + t];
            srow[g][t] = s;
            __syncthreads();
            if (t < 16) {
                int w0 = __builtin_amdgcn_cvt_pk_fp8_f32(srow[g][t * 4], srow[g][t * 4 + 1], 0, false);
                int w  = __builtin_amdgcn_cvt_pk_fp8_f32(srow[g][t * 4 + 2], srow[g][t * 4 + 3], w0, true);
                h8_dir[(size_t)n * 16 + t] = (unsigned)w;
            }
            if (t < 28) {
                int slot = t >> 2, hh = t & 3;
                float sc = 0.f;
#pragma unroll
                for (int d = 0; d < 16; ++d)
                    sc += srow[g][hh * 16 + d] * satt[slot * 64 + hh * 16 + d];
                s_dir[(size_t)n * 28 + t] = __float2half(sc);
            }
            __syncthreads();
        }
    }
}

// ============ k2: bucket totals + bases, 64 buckets x 4 threads per block ==
__global__ __launch_bounds__(256) void k2_kernel(
    const int* __restrict__ blockcnt, int* __restrict__ blockbase,
    int* __restrict__ bbase, int* __restrict__ btot, int* __restrict__ cursor)
{
    __shared__ int part[4][64];
    __shared__ int tots[64];
    __shared__ int scn[64];
    __shared__ int bw;
    const int tid = threadIdx.x;
    const int kq = tid >> 6, bl = tid & 63;   // 4 k-quarters x 64 buckets
    const int b = blockIdx.x * 64 + bl;
    const int K = NBK / 4;                    // 20 rows per quarter
    int ps = 0;
    if (b < NBUCK)
        for (int k = kq * K; k < kq * K + K; ++k)
            ps += blockcnt[(size_t)k * NBUCK + b];
    part[kq][bl] = ps;
    __syncthreads();
    if (tid < 64) {
        int t = part[0][tid] + part[1][tid] + part[2][tid] + part[3][tid];
        tots[tid] = t;
        scn[tid] = t;
    }
    __syncthreads();
    for (int off = 1; off < 64; off <<= 1) {
        int v = 0;
        if (tid < 64 && tid >= off) v = scn[tid - off];
        __syncthreads();
        if (tid < 64) scn[tid] += v;
        __syncthreads();
    }
    if (tid == 63) bw = atomicAdd(cursor, scn[63]);
    __syncthreads();
    if (b < NBUCK) {
        int bs = bw + scn[bl] - tots[bl];     // exclusive bucket base
        if (kq == 0) {
            bbase[b] = bs;
            btot[b] = tots[bl];
        }
        int run = bs;
        for (int q = 0; q < kq; ++q) run += part[q][bl];
        for (int k = kq * K; k < kq * K + K; ++k) {
            blockbase[(size_t)k * NBUCK + b] = run;
            run += blockcnt[(size_t)k * NBUCK + b];
        }
    }
}

// ============ k3: bucket scatter (LDS cursors, packed u32 entries) =========
__global__ __launch_bounds__(256) void k3_kernel(
    const int* __restrict__ e0, const int* __restrict__ e1,
    const int* __restrict__ e2, const int* __restrict__ e3,
    const int* __restrict__ e4, const int* __restrict__ blockbase,
    unsigned* __restrict__ bpair)
{
    __shared__ int cur[NBUCK];
    const int bid = blockIdx.x, tid = threadIdx.x;
    const int type = bid / BA, blk = bid % BA;
    const int* ei = type == 0 ? e0 : type == 1 ? e1 : type == 2 ? e2
                  : type == 3 ? e3 : e4;
    const int base = type == 0 ? 0 : type == 1 ? 50000 : type == 2 ? 100000
                   : type == 3 ? 200000 : 250000;
    const int* row = blockbase + (size_t)bid * NBUCK;
    for (int i = tid; i < NBUCK; i += 256) cur[i] = row[i];
    __syncthreads();
    const int4* s4 = (const int4*)ei;
    const int4* d4 = (const int4*)(ei + NE);
    for (int i = blk * 256 + tid; i < I4PT; i += BA * 256) {
        int4 s = s4[i];
        int4 d = d4[i];
        int g0 = base + d.x, g1 = base + d.y, g2 = base + d.z, g3 = base + d.w;
        int p0 = atomicAdd(&cur[g0 >> 6], 1);
        int p1 = atomicAdd(&cur[g1 >> 6], 1);
        int p2 = atomicAdd(&cur[g2 >> 6], 1);
        int p3 = atomicAdd(&cur[g3 >> 6], 1);
        bpair[p0] = ((unsigned)(g0 & 63) << 17) | (unsigned)s.x;
        bpair[p1] = ((unsigned)(g1 & 63) << 17) | (unsigned)s.y;
        bpair[p2] = ((unsigned)(g2 & 63) << 17) | (unsigned)s.z;
        bpair[p3] = ((unsigned)(g3 & 63) << 17) | (unsigned)s.w;
    }
}

// ============ k4: per-bucket counting sort -> perm + start/cnt =============
__global__ __launch_bounds__(256) void k4_kernel(
    const unsigned* __restrict__ bpair, const int* __restrict__ bbase,
    const int* __restrict__ btot, int* __restrict__ perm,
    int* __restrict__ start, int* __restrict__ cnt)
{
    __shared__ int h[64], sc[64], cu[64];
    const int b = blockIdx.x, tid = threadIdx.x;
    const int jb = bbase[b], n = btot[b];
    if (tid < 64) h[tid] = 0;
    __syncthreads();
    for (int i = tid; i < n; i += 256)
        atomicAdd(&h[bpair[jb + i] >> 17], 1);
    __syncthreads();
    if (tid == 0) {
        int r = 0;
        for (int i = 0; i < 64; ++i) { sc[i] = r; cu[i] = r; r += h[i]; }
    }
    __syncthreads();
    if (tid < 64) {
        int dg = b * 64 + tid;
        if (dg < NDST_TOTAL) {
            start[dg] = jb + sc[tid];
            cnt[dg] = h[tid];
        }
    }
    for (int i = tid; i < n; i += 256) {
        unsigned p = bpair[jb + i];
        int pos = atomicAdd(&cu[p >> 17], 1);
        perm[jb + pos] = (int)(p & 0x1FFFF);
    }
}

// ============ fused aggregation: fp8 rows, fp16 scores, 8 edges/iter =======
__global__ __launch_bounds__(256) void agg_all_kernel(
    const int* __restrict__ perm, const int* __restrict__ start,
    const int* __restrict__ cnttot,
    const unsigned* __restrict__ h8_ing, const unsigned* __restrict__ h8_dir,
    const __half* __restrict__ s_ing, const __half* __restrict__ s_dir,
    const float* __restrict__ Wk, const float* __restrict__ bk,
    float* __restrict__ pool_ing, float* __restrict__ pool_dir,
    float* __restrict__ sem_dir)
{
    __shared__ float sWk[64 * 64];
    __shared__ float srow[4][64];
    __shared__ float sred[4][64];
    const int t = threadIdx.x & 63, w = threadIdx.x >> 6;
    const int g  = t >> 4;       // edge group 0..3
    const int l4 = t & 15;       // feature quad: 4*l4 .. 4*l4+3
    const int hq = l4 >> 2;      // head of my features
    for (int i = threadIdx.x; i < 4096; i += 256) sWk[i] = Wk[i];
    const float bkf = bk[t];
    float p_ing = 0.f;
    float p0 = 0.f, p1 = 0.f, p2 = 0.f, p3 = 0.f;
    float m0 = 0.f, m1 = 0.f, m2 = 0.f, m3 = 0.f;
    __syncthreads();
    const int nwaves = gridDim.x * 4;
    for (int d = blockIdx.x * 4 + w; d < NDST_TOTAL; d += nwaves) {
        int type, ld;
        const __half *ssrc, *sdst;
        const unsigned* hsrc;
        int ss, soff, ds, doff;
        if (d < 50000)       { type = 0; ld = d;          ssrc = s_ing; ss = 12; soff = 0;  sdst = s_dir; ds = 28; doff = 0;  hsrc = h8_ing; }
        else if (d < 100000) { type = 1; ld = d - 50000;  ssrc = s_ing; ss = 12; soff = 4;  sdst = s_dir; ds = 28; doff = 4;  hsrc = h8_ing; }
        else if (d < 200000) { type = 2; ld = d - 100000; ssrc = s_dir; ss = 28; soff = 8;  sdst = s_ing; ds = 12; doff = 8;  hsrc = h8_dir; }
        else if (d < 250000) { type = 3; ld = d - 200000; ssrc = s_dir; ss = 28; soff = 12; sdst = s_dir; ds = 28; doff = 16; hsrc = h8_dir; }
        else                 { type = 4; ld = d - 250000; ssrc = s_dir; ss = 28; soff = 20; sdst = s_dir; ds = 28; doff = 24; hsrc = h8_dir; }
        float adst = __half2float(sdst[(size_t)ld * ds + doff + hq]);
        int jb = start[d], je = jb + cnttot[d];
        float4 acc = make_float4(0.f, 0.f, 0.f, 0.f);
        float dsum = 0.f;
        for (int j = jb; j < je; j += 8) {
            int j0 = j + g, j1 = j + 4 + g;
            bool v0 = j0 < je, v1 = j1 < je;
            int s0 = perm[v0 ? j0 : je - 1];
            int s1 = perm[v1 ? j1 : je - 1];
            float c0 = __half2float(ssrc[(size_t)s0 * ss + soff + hq]);
            float c1 = __half2float(ssrc[(size_t)s1 * ss + soff + hq]);
            unsigned u0 = hsrc[(size_t)s0 * 16 + l4];
            unsigned u1 = hsrc[(size_t)s1 * 16 + l4];
            float a0 = c0 + adst; a0 = a0 > 0.f ? a0 : 0.2f * a0;
            float a1 = c1 + adst; a1 = a1 > 0.f ? a1 : 0.2f * a1;
            float e0 = v0 ? __expf(a0) : 0.f;
            float e1 = v1 ? __expf(a1) : 0.f;
            dsum += e0 + e1;
            v2f lo0 = __builtin_amdgcn_cvt_pk_f32_fp8((int)u0, false);
            v2f hi0 = __builtin_amdgcn_cvt_pk_f32_fp8((int)u0, true);
            v2f lo1 = __builtin_amdgcn_cvt_pk_f32_fp8((int)u1, false);
            v2f hi1 = __builtin_amdgcn_cvt_pk_f32_fp8((int)u1, true);
            acc.x += lo0.x * e0 + lo1.x * e1;
            acc.y += lo0.y * e0 + lo1.y * e1;
            acc.z += hi0.x * e0 + hi1.x * e1;
            acc.w += hi0.y * e0 + hi1.y * e1;
        }
#pragma unroll
        for (int mask = 16; mask <= 32; mask <<= 1) {
            acc.x += __shfl_xor(acc.x, mask, 64);
            acc.y += __shfl_xor(acc.y, mask, 64);
            acc.z += __shfl_xor(acc.z, mask, 64);
            acc.w += __shfl_xor(acc.w, mask, 64);
            dsum  += __shfl_xor(dsum,  mask, 64);
        }
        float inv = 1.f / (dsum + 1e-16f);
        float4 v4 = make_float4(fmaxf(acc.x * inv, 0.f), fmaxf(acc.y * inv, 0.f),
                                fmaxf(acc.z * inv, 0.f), fmaxf(acc.w * inv, 0.f));
        if (g == 0) *(float4*)&srow[w][l4 * 4] = v4;  // rebroadcast layout
        float v = srow[w][t];                          // wave-coherent LDS
        if (type == 2) {
            p_ing += v;
        } else {
            float a2 = bkf;
#pragma unroll
            for (int k = 0; k < 64; ++k) a2 += srow[w][k] * sWk[k * 64 + t];
            float tv = tanhf(a2);
            if (type == 0)      { p0 += v; m0 += tv; }
            else if (type == 1) { p1 += v; m1 += tv; }
            else if (type == 3) { p2 += v; m2 += tv; }
            else                { p3 += v; m3 += tv; }
        }
    }
    float vals[9] = { p_ing, p0, p1, p2, p3, m0, m1, m2, m3 };
    float* outs[9] = { pool_ing, pool_dir, pool_dir + 64, pool_dir + 128,
                       pool_dir + 192, sem_dir, sem_dir + 64, sem_dir + 128,
                       sem_dir + 192 };
    for (int i = 0; i < 9; ++i) {
        __syncthreads();
        sred[w][t] = vals[i];
        __syncthreads();
        if (w == 0)
            atomicAdd(&outs[i][t], sred[0][t] + sred[1][t] + sred[2][t] + sred[3][t]);
    }
}

// ============ final: semantic softmax + pools + VAE head ===================
__global__ __launch_bounds__(64) void final_kernel(
    const float* __restrict__ pool_ing, const float* __restrict__ pool_dir,
    const float* __restrict__ sem_dir, const float* __restrict__ q,
    const float* __restrict__ cond, const float* __restrict__ eps,
    const float* __restrict__ W_mu, const float* __restrict__ b_mu,
    const float* __restrict__ W_lv, const float* __restrict__ b_lv,
    const float* __restrict__ W_fc3, const float* __restrict__ b_fc3,
    const float* __restrict__ W_fc2, const float* __restrict__ b_fc2,
    float* __restrict__ out)
{
    __shared__ float gr[136];
    __shared__ float sc[4], attn[4];
    __shared__ float z[32], hfc[64];
    int t = threadIdx.x;  // 64 threads
    if (t < 4) {
        float s = 0.f;
        for (int f = 0; f < 64; ++f)
            s += (sem_dir[t * 64 + f] / (float)N_DIR) * q[f];
        sc[t] = s;
    }
    gr[t] = pool_ing[t] / (float)N_ING;   // out_ing == o_cont (T=1 softmax)
    __syncthreads();
    if (t == 0) {
        float m = fmaxf(fmaxf(sc[0], sc[1]), fmaxf(sc[2], sc[3]));
        float ssum = 0.f;
        for (int i = 0; i < 4; ++i) { attn[i] = expf(sc[i] - m); ssum += attn[i]; }
        for (int i = 0; i < 4; ++i) attn[i] /= ssum;
    }
    __syncthreads();
    {
        float v = 0.f;
        for (int tt = 0; tt < 4; ++tt)
            v += attn[tt] * (pool_dir[tt * 64 + t] / (float)N_DIR);
        gr[64 + t] = v;
    }
    if (t < 8) gr[128 + t] = cond[t];
    __syncthreads();
    if (t < 32) {
        float m = b_mu[t], lv = b_lv[t];
        for (int i = 0; i < 136; ++i) {
            float g = gr[i];
            m  += g * W_mu[i * 32 + t];
            lv += g * W_lv[i * 32 + t];
        }
        out[16 + t] = m;
        out[48 + t] = lv;
        z[t] = m + eps[t] * expf(0.5f * lv);
    }
    __syncthreads();
    {
        float v = b_fc3[t];
        for (int j = 0; j < 32; ++j) v += z[j] * W_fc3[j * 64 + t];
        hfc[t] = fmaxf(v, 0.f);
    }
    __syncthreads();
    if (t < 16) {
        float v = b_fc2[t];
        for (int f = 0; f < 64; ++f) v += hfc[f] * W_fc2[f * 16 + t];
        out[t] = tanhf(v);
    }
}

extern "C" void kernel_launch(void* const* d_in, const int* in_sizes, int n_in,
                              void* d_out, int out_size, void* d_ws, size_t ws_size,
                              hipStream_t stream) {
    const float* x_ing = (const float*)d_in[0];
    const float* x_dir = (const float*)d_in[1];
    const float* cond  = (const float*)d_in[2];
    const float* eps   = (const float*)d_in[3];
    const int* ei_cooc     = (const int*)d_in[4];
    const int* ei_used     = (const int*)d_in[5];
    const int* ei_contains = (const int*)d_in[6];
    const int* ei_pairs    = (const int*)d_in[7];
    const int* ei_follows  = (const int*)d_in[8];
    const float* W_pi = (const float*)d_in[9];
    const float* b_pi = (const float*)d_in[10];
    const float* W_pd = (const float*)d_in[11];
    const float* b_pd = (const float*)d_in[12];
    const float* Wk   = (const float*)d_in[13];
    const float* bk   = (const float*)d_in[14];
    const float* q    = (const float*)d_in[15];
    const float* W_mu = (const float*)d_in[16];
    const float* b_mu = (const float*)d_in[17];
    const float* W_lv = (const float*)d_in[18];
    const float* b_lv = (const float*)d_in[19];
    const float* W_fc3 = (const float*)d_in[20];
    const float* b_fc3 = (const float*)d_in[21];
    const float* W_fc2 = (const float*)d_in[22];
    const float* b_fc2 = (const float*)d_in[23];
    const float* as_cooc     = (const float*)d_in[24];
    const float* ad_cooc     = (const float*)d_in[25];
    const float* as_used     = (const float*)d_in[26];
    const float* ad_used     = (const float*)d_in[27];
    const float* as_contains = (const float*)d_in[28];
    const float* ad_contains = (const float*)d_in[29];
    const float* as_pairs    = (const float*)d_in[30];
    const float* ad_pairs    = (const float*)d_in[31];
    const float* as_follows  = (const float*)d_in[32];
    const float* ad_follows  = (const float*)d_in[33];

    // ---- workspace layout ----
    unsigned* bpair = (unsigned*)d_ws;                        // 5M u32 (20 MB)
    unsigned* h8_ing = bpair + (size_t)5 * NE;                // N_ING*16 u32
    unsigned* h8_dir = h8_ing + (size_t)N_ING * 16;           // N_DIR*16
    __half* s_ing = (__half*)(h8_dir + (size_t)N_DIR * 16);   // N_ING*12 fp16
    __half* s_dir = s_ing + (size_t)N_ING * 12;               // N_DIR*28 fp16
    int*   perm  = (int*)(s_dir + (size_t)N_DIR * 28);        // 5M
    int*   blockcnt  = perm + (size_t)5 * NE;                 // 80*4688
    int*   blockbase = blockcnt + (size_t)NBK * NBUCK;        // 80*4688
    int*   bbase  = blockbase + (size_t)NBK * NBUCK;          // 4688
    int*   btot   = bbase + NBUCK;                            // 4688
    int*   start  = btot + NBUCK;                             // 300K
    int*   cnt    = start + NDST_TOTAL;                       // 300K
    int*   cursor = cnt + NDST_TOTAL;                         // 1  (zeroed region)
    float* pool_ing = (float*)(cursor + 1);                   // 64
    float* pool_dir = pool_ing + 64;                          // 4*64
    float* sem_dir  = pool_dir + 256;                         // 4*64

    // tiny memset: cursor + pools
    hipMemsetAsync(cursor, 0, (1 + 64 + 256 + 256) * sizeof(int), stream);

    // kA: bucket histogram (LDS-only atomics) + fused proj/fp8/fp16-score
    kA_kernel<<<NBK + PB_ING + PB_DIR, 256, 0, stream>>>(
        ei_cooc, ei_used, ei_contains, ei_pairs, ei_follows, blockcnt,
        x_ing, W_pi, b_pi, as_cooc, as_used, ad_contains, h8_ing, s_ing,
        x_dir, W_pd, b_pd, ad_cooc, ad_used, as_contains, as_pairs, ad_pairs,
        as_follows, ad_follows, h8_dir, s_dir);

    // k2: bucket scan -> bases (64 buckets x 4 threads per block)
    k2_kernel<<<(NBUCK + 63) / 64, 256, 0, stream>>>(
        blockcnt, blockbase, bbase, btot, cursor);

    // k3: bucket scatter (LDS cursors, u32 packed)
    k3_kernel<<<NBK, 256, 0, stream>>>(
        ei_cooc, ei_used, ei_contains, ei_pairs, ei_follows, blockbase, bpair);

    // k4: per-bucket counting sort -> perm + start/cnt
    k4_kernel<<<NBUCK, 256, 0, stream>>>(bpair, bbase, btot, perm, start, cnt);

    // agg over all 300K dst segments
    agg_all_kernel<<<2048, 256, 0, stream>>>(
        perm, start, cnt, h8_ing, h8_dir, s_ing, s_dir, Wk, bk,
        pool_ing, pool_dir, sem_dir);

    final_kernel<<<1, 64, 0, stream>>>(
        pool_ing, pool_dir, sem_dir, q, cond, eps,
        W_mu, b_mu, W_lv, b_lv, W_fc3, b_fc3, W_fc2, b_fc2, (float*)d_out);
}